// Round 19
// baseline (275.403 us; speedup 1.0000x reference)
//
#include <hip/hip_runtime.h>
#include <hip/hip_bf16.h>
#include <math.h>

#define TS 256
#define HW 65536
#define CIN 64
#define EPSV 1e-5f
#define XPITCH 258   // padded row width (cols -1..256); rows padded too (i = -1..256)
// xbf layout: chunk-major planes: ((b*8 + chunk)*258 + row)*XPITCH + col, 8 ch contiguous (16 B)

typedef __attribute__((ext_vector_type(8))) short bf16x8;
typedef __attribute__((ext_vector_type(4))) float f32x4;
typedef __attribute__((ext_vector_type(16))) float f32x16;
typedef __attribute__((ext_vector_type(4))) unsigned short u16x4;
typedef unsigned short ushort_t;

__device__ __forceinline__ float silu_f(float v){ return v / (1.0f + expf(-v)); }
__device__ __forceinline__ ushort_t f2bf(float f){
    __hip_bfloat16 h = __float2bfloat16(f);
    return *reinterpret_cast<ushort_t*>(&h);
}
__device__ __forceinline__ float bf2f(ushort_t u){
    unsigned int t = ((unsigned int)u) << 16;
    return __uint_as_float(t);
}

// ======== k_pre: fused {offset-conv partials + x->bf16 convert} | {halo zeroing} ========
// main blocks (0..4095): b*8+chunk = blk&31, i0 = (blk>>5)*2; offp math is r14-verbatim.
__global__ __launch_bounds__(256) void k_pre(const float* __restrict__ x,
        const float* __restrict__ owx, const float* __restrict__ owy,
        float* __restrict__ poff, ushort_t* __restrict__ xbf){
    int blk = blockIdx.x;
    int tid = threadIdx.x;
    if (blk < 4096){
        __shared__ float xs[8][4][258];
        __shared__ float wsm[4][8][9];
        int by = blk & 31;            // b*8 + chunk
        int b = by >> 3, chunk = by & 7;
        int i0 = (blk >> 5) * 2;
        for (int idx = tid; idx < 4*8*9; idx += 256){
            int o = idx / 72;
            int rem = idx - o*72;
            int c = rem / 9, tap = rem - c*9;
            int morph = o >> 1;
            int ch = (o==0)?0:(o==1)?2:(o==2)?3:5;
            const float* w = morph ? owy : owx;
            wsm[o][c][tap] = w[(ch*64 + chunk*8 + c)*9 + tap];
        }
        for (int idx = tid; idx < 8*4*258; idx += 256){
            int c = idx / 1032;
            int rem = idx - c*1032;
            int rr = rem / 258, col = rem - rr*258;
            int gy = i0 + rr - 1, gx = col - 1;
            float v = 0.f;
            if (gy >= 0 && gy < 256 && gx >= 0 && gx < 256)
                v = x[((size_t)(b*64 + chunk*8 + c))*HW + gy*256 + gx];
            xs[c][rr][col] = v;
        }
        __syncthreads();
        float acc[4][2];
        #pragma unroll
        for (int o = 0; o < 4; ++o){ acc[o][0]=0.f; acc[o][1]=0.f; }
        int j = tid;
        #pragma unroll
        for (int c = 0; c < 8; ++c){
            float vrow[4][3];
            #pragma unroll
            for (int rr = 0; rr < 4; ++rr){
                vrow[rr][0] = xs[c][rr][j];
                vrow[rr][1] = xs[c][rr][j+1];
                vrow[rr][2] = xs[c][rr][j+2];
            }
            #pragma unroll
            for (int o = 0; o < 4; ++o){
                const float* wr = wsm[o][c];
                #pragma unroll
                for (int ky = 0; ky < 3; ++ky){
                    #pragma unroll
                    for (int kx = 0; kx < 3; ++kx){
                        float wv = wr[ky*3+kx];
                        acc[o][0] += wv * vrow[ky][kx];
                        acc[o][1] += wv * vrow[ky+1][kx];
                    }
                }
            }
        }
        #pragma unroll
        for (int o = 0; o < 4; ++o){
            size_t base = ((size_t)((chunk*4 + o)*4 + b))*HW;
            poff[base + (size_t)i0*256 + j]     = acc[o][0];
            poff[base + (size_t)(i0+1)*256 + j] = acc[o][1];
        }
        // bf16 convert the 2 data rows into chunk-major xbf (coalesced 16B/thread)
        #pragma unroll
        for (int r2 = 0; r2 < 2; ++r2){
            bf16x8 pk;
            #pragma unroll
            for (int c = 0; c < 8; ++c)
                pk[c] = (short)f2bf(xs[c][r2+1][j+1]);
            *(bf16x8*)(xbf + ((((size_t)(b*8 + chunk)*258) + (i0 + r2 + 1))*XPITCH + 1 + j)*8) = pk;
        }
    } else {
        // halo zeroing, chunk-major layout: 32 planes; full rows 0/257; cols 0/257 of rows 1..256
        int base = (blk - 4096) * 1024;
        #pragma unroll
        for (int k = 0; k < 4; ++k){
            int h = base + k*256 + tid;
            if (h < 132096){
                int plane = h / 4128;
                int rem = h - plane*4128;
                int r = (rem >= 2064) ? 257 : 0;
                int e = (rem >= 2064) ? rem - 2064 : rem;
                xbf[((size_t)plane*258 + r)*2064 + e] = 0;
            } else if (h < 263168){
                int h2 = h - 132096;
                int plane = h2 >> 12;
                int rem = h2 & 4095;
                int row = rem >> 4;
                int rem2 = rem & 15;
                int colsel = rem2 >> 3;
                int c = rem2 & 7;
                xbf[(((size_t)plane*258 + row + 1)*XPITCH + (colsel ? 257 : 0))*8 + c] = 0;
            }
        }
    }
}

// ---------------- weight repacks, merged ----
__global__ __launch_bounds__(256) void k_wpack(const float* __restrict__ w0,
        const float* __restrict__ wx, const float* __restrict__ wy,
        ushort_t* __restrict__ w0bf, ushort_t* __restrict__ wbfx, ushort_t* __restrict__ wbfy){
    int idx = blockIdx.x*256 + threadIdx.x;   // 61440 total
    if (idx < 36864){
        int r = idx >> 12;
        int rem = idx & 4095;
        int o = rem >> 6, c = rem & 63;
        w0bf[idx] = f2bf(w0[(o*64 + c)*9 + r]);
    } else {
        int k2 = idx - 36864;   // 0..24575
        int set = k2 / 12288;
        int rem = k2 - set*12288;
        int o = rem / 192;
        int k = rem - o*192;
        int t = k >> 6, c = k & 63;
        const float* w = set ? wy : wx;
        ushort_t* dst = set ? wbfy : wbfx;
        dst[rem] = f2bf(w[(o*64 + c)*3 + t]);
    }
}

// ================= k_mid: {conv0 32x32 MFMA (0..2047)} | {offred (2048..6143), planes 0,2 only} =================
__global__ __launch_bounds__(256) void k_mid(
        const ushort_t* __restrict__ xbf, const ushort_t* __restrict__ w0bf,
        const float* __restrict__ g0, const float* __restrict__ b0,
        const float* __restrict__ m0, const float* __restrict__ v0,
        const float* __restrict__ poff,
        const float* __restrict__ ogx, const float* __restrict__ ovx,
        const float* __restrict__ obx, const float* __restrict__ omx,
        const float* __restrict__ obbx,
        const float* __restrict__ ogy, const float* __restrict__ ovy,
        const float* __restrict__ oby, const float* __restrict__ omy,
        const float* __restrict__ obby,
        float* __restrict__ off0, float* __restrict__ off1,
        float* __restrict__ out){
    __shared__ __align__(16) ushort_t Xs[3*130*64];
    int blk = blockIdx.x;
    int tid = threadIdx.x;
    if (blk < 2048){
        int id2 = ((blk & 7) << 8) + (blk >> 3);
        int b  = id2 >> 9;
        int i  = (id2 >> 1) & 255;
        int jh = id2 & 1;
        int j0h = jh*128;
        int wv = tid >> 6;
        int lane = tid & 63;
        int l31 = lane & 31;
        int kh = lane >> 5;
        int obase = (wv & 1) * 32;
        int pxb = (wv >> 1) * 64;

        // stage 3 rows x 130 px x 64 ch from chunk-major xbf (XOR-swizzled ds_write_b128)
        for (int idx = tid; idx < 3120; idx += 256){
            int rr = idx / 1040;
            int rem = idx - rr*1040;
            int p = rem >> 3, cgrp = rem & 7;
            bf16x8 v = *(const bf16x8*)(xbf + ((((size_t)(b*8 + cgrp)*258) + (i + rr))*XPITCH + j0h + p)*8);
            int byte = rr*16640 + p*128 + ((cgrp*16) ^ ((p & 7) << 4));
            *(bf16x8*)((char*)Xs + byte) = v;
        }
        __syncthreads();

        f32x16 acc0, acc1;
        #pragma unroll
        for (int e = 0; e < 16; ++e){ acc0[e] = 0.f; acc1[e] = 0.f; }

        #pragma unroll
        for (int r = 0; r < 9; ++r){
            const int rr = r/3, dx = r%3 - 1;
            bf16x8 af[4];
            #pragma unroll
            for (int kg = 0; kg < 4; ++kg)
                af[kg] = *(const bf16x8*)(w0bf + (size_t)r*4096 + (obase + l31)*64 + kg*16 + kh*8);
            #pragma unroll
            for (int kg = 0; kg < 4; ++kg){
                int cb = kg*32 + kh*16;
                int p0_ = pxb + l31 + dx + 1;
                bf16x8 b0_ = *(const bf16x8*)((char*)Xs + rr*16640 + p0_*128 + (cb ^ ((p0_ & 7) << 4)));
                acc0 = __builtin_amdgcn_mfma_f32_32x32x16_bf16(af[kg], b0_, acc0, 0, 0, 0);
                int p1_ = p0_ + 32;
                bf16x8 b1_ = *(const bf16x8*)((char*)Xs + rr*16640 + p1_*128 + (cb ^ ((p1_ & 7) << 4)));
                acc1 = __builtin_amdgcn_mfma_f32_32x32x16_bf16(af[kg], b1_, acc1, 0, 0, 0);
            }
        }
        #pragma unroll
        for (int reg = 0; reg < 16; ++reg){
            int o = obase + (reg & 3) + 8*(reg >> 2) + 4*kh;
            float s = g0[o] * rsqrtf(v0[o] + EPSV);
            float bi = b0[o] - m0[o]*s;
            int j = j0h + pxb + l31;
            out[((size_t)(b*192 + o))*HW + i*TS + j]      = silu_f(acc0[reg]*s + bi);
            out[((size_t)(b*192 + o))*HW + i*TS + j + 32] = silu_f(acc1[reg]*s + bi);
        }
    } else {
        int idx = (blk - 2048)*256 + tid;
        int px = idx & 65535;
        int t2 = idx >> 16;
        int b = t2 & 3;
        int o6 = t2 >> 2;
        float s_ = 0.f;
        #pragma unroll
        for (int chunk = 0; chunk < 8; ++chunk)
            s_ += poff[((size_t)((chunk*4 + o6)*4 + b))*HW + px];
        int morph = o6 >> 1;
        int ch = (o6==0)?0:(o6==1)?2:(o6==2)?3:5;
        const float* og_ = morph? ogy:ogx; const float* ov_ = morph? ovy:ovx;
        const float* ob_ = morph? oby:obx; const float* om_ = morph? omy:omx;
        const float* obb_ = morph? obby:obbx;
        float sc = og_[ch]*rsqrtf(ov_[ch]+EPSV);
        float bi = (ob_[ch]-om_[ch])*sc + obb_[ch];
        int pl = (o6 & 1)*2;
        float* dst = (morph? off1:off0) + ((size_t)(b*3+pl))*HW;
        dst[px] = tanhf(s_*sc + bi);
    }
}

// ---------------- DSC both morphs: LDS-staged local window gather -> LDS bf16 -> MFMA ----------------
__global__ __launch_bounds__(256) void k_dsc2m(const ushort_t* __restrict__ xbf,
        const float* __restrict__ off0, const float* __restrict__ off1,
        const ushort_t* __restrict__ wbfx, const ushort_t* __restrict__ wbfy,
        const float* __restrict__ bwx, const float* __restrict__ bwy,
        ushort_t* __restrict__ zbuf, float* __restrict__ part){
    __shared__ __align__(16) ushort_t Vt[3*64*64];
    __shared__ __align__(16) ushort_t Xg[7][4][64];
    int mz = blockIdx.z;
    int b = mz & 3;
    int morph = mz >> 2;
    int i = blockIdx.y;
    int j0 = blockIdx.x * 64;
    int tid = threadIdx.x;
    int lane16 = tid & 15;
    int pq = tid >> 4;
    const float fi = (float)i;
    const float* offm = morph ? off1 : off0;

    // stage the local xbf window (batch 0 planes = chunks 0..7)
    if (morph == 0){
        int vec = tid >> 4;       // 0..15
        int s = vec >> 2, cs = vec & 3;
        int row = min(max(i - 1 + s, 0), 255);
        int col = min(max(i - 2 + cs, 0), 255);
        int chunk = lane16 >> 1, off8 = (lane16 & 1)*4;
        *(u16x4*)&Xg[s][cs][lane16*4] =
            *(const u16x4*)(xbf + (((size_t)chunk*258 + row + 1)*XPITCH + 1 + col)*8 + off8);
    } else {
        if (tid < 112){
            int s = tid >> 4;     // 0..6
            int row = min(max(i - 3 + s, 0), 255);
            int chunk = lane16 >> 1, off8 = (lane16 & 1)*4;
            *(u16x4*)&Xg[s][0][lane16*4] =
                *(const u16x4*)(xbf + (((size_t)chunk*258 + row + 1)*XPITCH + 1 + i)*8 + off8);
        }
    }
    __syncthreads();

    #pragma unroll
    for (int it = 0; it < 12; ++it){
        int pair = it*16 + pq;
        int t = pair >> 6, jloc = pair & 63;
        float y, wx1, wx0;
        int x0i, x1i;
        if (morph == 0){
            int j = j0 + jloc;
            float off = (t == 1) ? 0.f : offm[((size_t)(b*3 + t)*TS + i)*TS + j];
            y = fi + off;
            float vp = (t==0) ? -2.0f : ((t==1) ? -0.5f : 1.0f);
            float xf = fi + vp;
            float x0 = fminf(fmaxf(floorf(xf), 0.f), 255.f);
            float x1 = fminf(fmaxf(floorf(xf) + 1.f, 0.f), 255.f);
            wx1 = x1 - xf; wx0 = xf - x0;
            x0i = (int)x0; x1i = (int)x1;
        } else {
            int q = 3*(j0 + jloc) + t;
            int dl = q >> 8, jj = q & 255;
            float off = (dl == 1) ? 0.f : offm[((size_t)(b*3 + dl)*TS + i)*TS + jj];
            float vp = (dl==0) ? -2.0f : ((dl==1) ? -0.5f : 1.0f);
            y = fi + vp + off;
            wx1 = (i < 255) ? 1.f : 0.f; wx0 = 0.f;
            x0i = i; x1i = i;
        }
        float yf = floorf(y);
        float y0 = fminf(fmaxf(yf, 0.f), 255.f);
        float y1 = fminf(fmaxf(yf + 1.f, 0.f), 255.f);
        float wy1 = y1 - y, wy0 = y - y0;
        int y0i = (int)y0, y1i = (int)y1;
        int c0 = lane16*4;
        int rbase = morph ? (i - 3) : (i - 1);
        int rs0 = y0i - rbase;
        int rs1 = y1i - rbase;
        int cs0 = morph ? 0 : (x0i - (i - 2));
        u16x4 a  = *(const u16x4*)&Xg[rs0][cs0][c0];
        u16x4 c_ = *(const u16x4*)&Xg[rs1][cs0][c0];
        float v[4];
        if (morph == 0 && wx0 != 0.f){
            int cs1 = x1i - (i - 2);
            u16x4 bv = *(const u16x4*)&Xg[rs0][cs1][c0];
            u16x4 d  = *(const u16x4*)&Xg[rs1][cs1][c0];
            #pragma unroll
            for (int k = 0; k < 4; ++k)
                v[k] = wy1*(wx1*bf2f(a[k]) + wx0*bf2f(bv[k]))
                     + wy0*(wx1*bf2f(c_[k]) + wx0*bf2f(d[k]));
        } else {
            #pragma unroll
            for (int k = 0; k < 4; ++k)
                v[k] = wx1*(wy1*bf2f(a[k]) + wy0*bf2f(c_[k]));
        }
        unsigned int lo = (unsigned int)f2bf(v[0]) | ((unsigned int)f2bf(v[1]) << 16);
        unsigned int hi = (unsigned int)f2bf(v[2]) | ((unsigned int)f2bf(v[3]) << 16);
        int cbyte = (c0*2) ^ ((jloc & 7) << 4);
        uint2 pk; pk.x = lo; pk.y = hi;
        *(uint2*)((char*)Vt + t*8192 + jloc*128 + cbyte) = pk;
    }
    __syncthreads();

    const ushort_t* wbf = morph ? wbfy : wbfx;
    const float* wb = morph ? bwy : bwx;
    ushort_t* zb = zbuf + (size_t)morph*4*64*HW;

    int wv = tid >> 6;
    int lane = tid & 63;
    int l15 = lane & 15, lhi = lane >> 4;
    int mi = wv;
    f32x4 acc[4];
    #pragma unroll
    for (int ni = 0; ni < 4; ++ni) acc[ni] = (f32x4){0.f,0.f,0.f,0.f};
    bf16x8 af[6];
    #pragma unroll
    for (int ks = 0; ks < 6; ++ks)
        af[ks] = *(const bf16x8*)(wbf + (mi*16 + l15)*192 + ks*32 + lhi*8);
    #pragma unroll
    for (int ks = 0; ks < 6; ++ks){
        int t = ks >> 1;
        int cbyte = ((ks & 1)*32 + lhi*8)*2;
        #pragma unroll
        for (int ni = 0; ni < 4; ++ni){
            int j = ni*16 + l15;
            bf16x8 bfr = *(const bf16x8*)((char*)Vt + t*8192 + j*128 + (cbyte ^ ((j & 7) << 4)));
            acc[ni] = __builtin_amdgcn_mfma_f32_16x16x32_bf16(af[ks], bfr, acc[ni], 0, 0, 0);
        }
    }
    float rsum[4], rsq[4];
    #pragma unroll
    for (int reg = 0; reg < 4; ++reg){
        int o = mi*16 + lhi*4 + reg;
        float bias = wb[o];
        float rs = 0.f, rq = 0.f;
        #pragma unroll
        for (int ni = 0; ni < 4; ++ni){
            int j = j0 + ni*16 + l15;
            float val = acc[ni][reg] + bias;
            zb[((size_t)b*64 + o)*HW + i*TS + j] = f2bf(val);
            rs += val; rq += val*val;
        }
        #pragma unroll
        for (int m = 1; m < 16; m <<= 1){
            rs += __shfl_xor(rs, m, 64);
            rq += __shfl_xor(rq, m, 64);
        }
        rsum[reg] = rs; rsq[reg] = rq;
    }
    if (l15 == 0){
        float ts = rsum[0]+rsum[1]+rsum[2]+rsum[3];
        float tq = rsq[0]+rsq[1]+rsq[2]+rsq[3];
        int g = mi*4 + lhi;
        size_t slot = (((size_t)(morph*4 + b)*16 + g)*1024) + (blockIdx.y*4 + blockIdx.x);
        part[slot*2]   = ts;
        part[slot*2+1] = tq;
    }
}

// ---------------- GN final: reduce 1024 partials per (m,b,g) ----------------
__global__ __launch_bounds__(256) void k_gnfinal2(const float* __restrict__ part, float* __restrict__ stats){
    int slot = blockIdx.x;
    float s = 0.f, q = 0.f;
    for (int k = threadIdx.x; k < 1024; k += 256){
        s += part[((size_t)slot*1024 + k)*2];
        q += part[((size_t)slot*1024 + k)*2 + 1];
    }
    #pragma unroll
    for (int d = 32; d > 0; d >>= 1){ s += __shfl_down(s, d, 64); q += __shfl_down(q, d, 64); }
    __shared__ float rs[4], rq[4];
    int lane = threadIdx.x & 63, wv = threadIdx.x >> 6;
    if (lane == 0){ rs[wv] = s; rq[wv] = q; }
    __syncthreads();
    if (threadIdx.x == 0){
        float S = rs[0]+rs[1]+rs[2]+rs[3];
        float Q = rq[0]+rq[1]+rq[2]+rq[3];
        float inv = 1.f/262144.f;
        float mean = S*inv;
        float var = Q*inv - mean*mean;
        stats[slot*2] = mean;
        stats[slot*2+1] = rsqrtf(var + EPSV);
    }
}

// ---------------- GN apply: read bf16 z, write f32 out (both morphs) ----------------
__global__ __launch_bounds__(256) void k_gnapply(float* __restrict__ dout, const ushort_t* __restrict__ zb,
        const float* __restrict__ stats,
        const float* __restrict__ ggx, const float* __restrict__ gbx,
        const float* __restrict__ ggy, const float* __restrict__ gby){
    int idx = blockIdx.x*256 + threadIdx.x;
    int pix4 = idx & 16383;
    int chb = idx >> 14;
    int ch = chb & 127;
    int b = chb >> 7;
    int m = ch >> 6;
    int cc = ch & 63;
    int g = cc >> 2;
    const float* gg = m ? ggy : ggx;
    const float* gb = m ? gby : gbx;
    int si = ((m*4 + b)*16 + g)*2;
    float mean = stats[si], rsig = stats[si+1];
    float sc = rsig * gg[cc];
    float bi = gb[cc] - mean*sc;
    u16x4 zv = *(const u16x4*)(zb + (((size_t)(m*4 + b)*64 + cc)*HW) + (size_t)pix4*4);
    float4 v;
    v.x = silu_f(bf2f(zv[0])*sc + bi);
    v.y = silu_f(bf2f(zv[1])*sc + bi);
    v.z = silu_f(bf2f(zv[2])*sc + bi);
    v.w = silu_f(bf2f(zv[3])*sc + bi);
    float4* ptr = (float4*)(dout + ((size_t)(b*192 + 64 + ch))*HW) + pix4;
    *ptr = v;
}

extern "C" void kernel_launch(void* const* d_in, const int* in_sizes, int n_in,
                              void* d_out, int out_size, void* d_ws, size_t ws_size,
                              hipStream_t stream){
    const float* x    = (const float*)d_in[0];
    const float* w0   = (const float*)d_in[1];
    const float* g0   = (const float*)d_in[2];
    const float* b0   = (const float*)d_in[3];
    const float* m0   = (const float*)d_in[4];
    const float* v0   = (const float*)d_in[5];
    const float* owx  = (const float*)d_in[6];
    const float* obx  = (const float*)d_in[7];
    const float* ogx  = (const float*)d_in[8];
    const float* obbx = (const float*)d_in[9];
    const float* omx  = (const float*)d_in[10];
    const float* ovx  = (const float*)d_in[11];
    const float* wx   = (const float*)d_in[12];
    const float* bwx  = (const float*)d_in[13];
    const float* ggx  = (const float*)d_in[14];
    const float* gbx  = (const float*)d_in[15];
    const float* owy  = (const float*)d_in[16];
    const float* oby  = (const float*)d_in[17];
    const float* ogy  = (const float*)d_in[18];
    const float* obby = (const float*)d_in[19];
    const float* omy  = (const float*)d_in[20];
    const float* ovy  = (const float*)d_in[21];
    const float* wy   = (const float*)d_in[22];
    const float* bwy  = (const float*)d_in[23];
    const float* ggy  = (const float*)d_in[24];
    const float* gby  = (const float*)d_in[25];

    float* out = (float*)d_out;
    // ws layout (bytes) — xbf correctly sized now (fixes latent w0bf/xbf halo overlap):
    //   xbf   @ 0          : 34,080,768   (32 planes x 258 x 258 x 8 x 2)
    //   w0bf  @ 34,080,768 : 73,728
    //   wbfx  @ 34,154,496 : 24,576
    //   wbfy  @ 34,179,072 : 24,576
    //   off0  @ 34,203,648 : 3,145,728
    //   off1  @ 37,349,376 : 3,145,728
    //   poff  @ 40,495,104 : 33,554,432   (dead after k_mid)
    //   zbuf  @ 40,495,104 : 67,108,864   (aliases poff)
    //   part  @ 107,603,968: 1,048,576
    //   stats @ 108,652,544: 1,024
    ushort_t* xbf  = (ushort_t*)d_ws;
    ushort_t* w0bf = (ushort_t*)((char*)d_ws + 34080768);
    ushort_t* wbfx = (ushort_t*)((char*)d_ws + 34154496);
    ushort_t* wbfy = (ushort_t*)((char*)d_ws + 34179072);
    float* off0  = (float*)((char*)d_ws + 34203648);
    float* off1  = (float*)((char*)d_ws + 37349376);
    float* poff  = (float*)((char*)d_ws + 40495104);
    ushort_t* zbuf = (ushort_t*)((char*)d_ws + 40495104);
    float* part  = (float*)((char*)d_ws + 107603968);
    float* stats = (float*)((char*)d_ws + 108652544);
    (void)ws_size;

    // fused offp + x->bf16 + halos (4096 + 257 blocks)
    k_pre<<<4353, 256, 0, stream>>>(x, owx, owy, poff, xbf);
    k_wpack<<<240, 256, 0, stream>>>(w0, wx, wy, w0bf, wbfx, wbfy);
    // conv0 | offred (2048 + 4096 blocks)
    k_mid<<<6144, 256, 0, stream>>>(xbf, w0bf, g0, b0, m0, v0, poff,
        ogx, ovx, obx, omx, obbx,
        ogy, ovy, oby, omy, obby,
        off0, off1, out);
    k_dsc2m<<<dim3(4,256,8), 256, 0, stream>>>(xbf, off0, off1, wbfx, wbfy, bwx, bwy, zbuf, part);
    k_gnfinal2<<<128, 256, 0, stream>>>(part, stats);
    k_gnapply<<<32768, 256, 0, stream>>>(out, zbuf, stats, ggx, gbx, ggy, gby);
}

// Round 20
// 267.803 us; speedup vs baseline: 1.0284x; 1.0284x over previous
//
#include <hip/hip_runtime.h>
#include <hip/hip_bf16.h>
#include <math.h>

#define TS 256
#define HW 65536
#define CIN 64
#define EPSV 1e-5f
#define XPITCH 258   // padded row width (cols -1..256); rows padded too (i = -1..256)
// xbf layout: chunk-major planes: ((b*8 + chunk)*258 + row)*XPITCH + col, 8 ch contiguous (16 B)

typedef __attribute__((ext_vector_type(8))) short bf16x8;
typedef __attribute__((ext_vector_type(4))) float f32x4;
typedef __attribute__((ext_vector_type(16))) float f32x16;
typedef __attribute__((ext_vector_type(4))) unsigned short u16x4;
typedef unsigned short ushort_t;

__device__ __forceinline__ float silu_f(float v){ return v / (1.0f + expf(-v)); }
__device__ __forceinline__ ushort_t f2bf(float f){
    __hip_bfloat16 h = __float2bfloat16(f);
    return *reinterpret_cast<ushort_t*>(&h);
}
__device__ __forceinline__ float bf2f(ushort_t u){
    unsigned int t = ((unsigned int)u) << 16;
    return __uint_as_float(t);
}

// ======== k_pre: fused {offset-conv partials + x->bf16 convert} | {halo zeroing} ========
// main blocks (0..4095): by = blk>>7 (b*8+chunk), i0 = (blk&127)*2  — r14 k_offp dispatch order
__global__ __launch_bounds__(256) void k_pre(const float* __restrict__ x,
        const float* __restrict__ owx, const float* __restrict__ owy,
        float* __restrict__ poff, ushort_t* __restrict__ xbf){
    int blk = blockIdx.x;
    int tid = threadIdx.x;
    if (blk < 4096){
        __shared__ float xs[8][4][258];
        __shared__ float wsm[4][8][9];
        int by = blk >> 7;            // b*8 + chunk
        int b = by >> 3, chunk = by & 7;
        int i0 = (blk & 127) * 2;
        for (int idx = tid; idx < 4*8*9; idx += 256){
            int o = idx / 72;
            int rem = idx - o*72;
            int c = rem / 9, tap = rem - c*9;
            int morph = o >> 1;
            int ch = (o==0)?0:(o==1)?2:(o==2)?3:5;
            const float* w = morph ? owy : owx;
            wsm[o][c][tap] = w[(ch*64 + chunk*8 + c)*9 + tap];
        }
        for (int idx = tid; idx < 8*4*258; idx += 256){
            int c = idx / 1032;
            int rem = idx - c*1032;
            int rr = rem / 258, col = rem - rr*258;
            int gy = i0 + rr - 1, gx = col - 1;
            float v = 0.f;
            if (gy >= 0 && gy < 256 && gx >= 0 && gx < 256)
                v = x[((size_t)(b*64 + chunk*8 + c))*HW + gy*256 + gx];
            xs[c][rr][col] = v;
        }
        __syncthreads();
        float acc[4][2];
        #pragma unroll
        for (int o = 0; o < 4; ++o){ acc[o][0]=0.f; acc[o][1]=0.f; }
        int j = tid;
        #pragma unroll
        for (int c = 0; c < 8; ++c){
            float vrow[4][3];
            #pragma unroll
            for (int rr = 0; rr < 4; ++rr){
                vrow[rr][0] = xs[c][rr][j];
                vrow[rr][1] = xs[c][rr][j+1];
                vrow[rr][2] = xs[c][rr][j+2];
            }
            #pragma unroll
            for (int o = 0; o < 4; ++o){
                const float* wr = wsm[o][c];
                #pragma unroll
                for (int ky = 0; ky < 3; ++ky){
                    #pragma unroll
                    for (int kx = 0; kx < 3; ++kx){
                        float wv = wr[ky*3+kx];
                        acc[o][0] += wv * vrow[ky][kx];
                        acc[o][1] += wv * vrow[ky+1][kx];
                    }
                }
            }
        }
        #pragma unroll
        for (int o = 0; o < 4; ++o){
            size_t base = ((size_t)((chunk*4 + o)*4 + b))*HW;
            poff[base + (size_t)i0*256 + j]     = acc[o][0];
            poff[base + (size_t)(i0+1)*256 + j] = acc[o][1];
        }
        // bf16 convert the 2 data rows into chunk-major xbf (coalesced 16B/thread)
        #pragma unroll
        for (int r2 = 0; r2 < 2; ++r2){
            bf16x8 pk;
            #pragma unroll
            for (int c = 0; c < 8; ++c)
                pk[c] = (short)f2bf(xs[c][r2+1][j+1]);
            *(bf16x8*)(xbf + ((((size_t)(b*8 + chunk)*258) + (i0 + r2 + 1))*XPITCH + 1 + j)*8) = pk;
        }
    } else {
        // halo zeroing, chunk-major layout: 32 planes; full rows 0/257; cols 0/257 of rows 1..256
        int base = (blk - 4096) * 1024;
        #pragma unroll
        for (int k = 0; k < 4; ++k){
            int h = base + k*256 + tid;
            if (h < 132096){
                int plane = h / 4128;
                int rem = h - plane*4128;
                int r = (rem >= 2064) ? 257 : 0;
                int e = (rem >= 2064) ? rem - 2064 : rem;
                xbf[((size_t)plane*258 + r)*2064 + e] = 0;
            } else if (h < 263168){
                int h2 = h - 132096;
                int plane = h2 >> 12;
                int rem = h2 & 4095;
                int row = rem >> 4;
                int rem2 = rem & 15;
                int colsel = rem2 >> 3;
                int c = rem2 & 7;
                xbf[(((size_t)plane*258 + row + 1)*XPITCH + (colsel ? 257 : 0))*8 + c] = 0;
            }
        }
    }
}

// ---------------- weight repacks, merged ----
__global__ __launch_bounds__(256) void k_wpack(const float* __restrict__ w0,
        const float* __restrict__ wx, const float* __restrict__ wy,
        ushort_t* __restrict__ w0bf, ushort_t* __restrict__ wbfx, ushort_t* __restrict__ wbfy){
    int idx = blockIdx.x*256 + threadIdx.x;   // 61440 total
    if (idx < 36864){
        int r = idx >> 12;
        int rem = idx & 4095;
        int o = rem >> 6, c = rem & 63;
        w0bf[idx] = f2bf(w0[(o*64 + c)*9 + r]);
    } else {
        int k2 = idx - 36864;   // 0..24575
        int set = k2 / 12288;
        int rem = k2 - set*12288;
        int o = rem / 192;
        int k = rem - o*192;
        int t = k >> 6, c = k & 63;
        const float* w = set ? wy : wx;
        ushort_t* dst = set ? wbfy : wbfx;
        dst[rem] = f2bf(w[(o*64 + c)*3 + t]);
    }
}

// ================= k_mid: {conv0 32x32 MFMA (0..2047)} | {offred (2048..6143), planes 0,2 only} =================
__global__ __launch_bounds__(256) void k_mid(
        const ushort_t* __restrict__ xbf, const ushort_t* __restrict__ w0bf,
        const float* __restrict__ g0, const float* __restrict__ b0,
        const float* __restrict__ m0, const float* __restrict__ v0,
        const float* __restrict__ poff,
        const float* __restrict__ ogx, const float* __restrict__ ovx,
        const float* __restrict__ obx, const float* __restrict__ omx,
        const float* __restrict__ obbx,
        const float* __restrict__ ogy, const float* __restrict__ ovy,
        const float* __restrict__ oby, const float* __restrict__ omy,
        const float* __restrict__ obby,
        float* __restrict__ off0, float* __restrict__ off1,
        float* __restrict__ out){
    __shared__ __align__(16) ushort_t Xs[3*130*64];
    int blk = blockIdx.x;
    int tid = threadIdx.x;
    if (blk < 2048){
        int id2 = ((blk & 7) << 8) + (blk >> 3);
        int b  = id2 >> 9;
        int i  = (id2 >> 1) & 255;
        int jh = id2 & 1;
        int j0h = jh*128;
        int wv = tid >> 6;
        int lane = tid & 63;
        int l31 = lane & 31;
        int kh = lane >> 5;
        int obase = (wv & 1) * 32;
        int pxb = (wv >> 1) * 64;

        for (int idx = tid; idx < 3120; idx += 256){
            int rr = idx / 1040;
            int rem = idx - rr*1040;
            int p = rem >> 3, cgrp = rem & 7;
            bf16x8 v = *(const bf16x8*)(xbf + ((((size_t)(b*8 + cgrp)*258) + (i + rr))*XPITCH + j0h + p)*8);
            int byte = rr*16640 + p*128 + ((cgrp*16) ^ ((p & 7) << 4));
            *(bf16x8*)((char*)Xs + byte) = v;
        }
        __syncthreads();

        f32x16 acc0, acc1;
        #pragma unroll
        for (int e = 0; e < 16; ++e){ acc0[e] = 0.f; acc1[e] = 0.f; }

        #pragma unroll
        for (int r = 0; r < 9; ++r){
            const int rr = r/3, dx = r%3 - 1;
            bf16x8 af[4];
            #pragma unroll
            for (int kg = 0; kg < 4; ++kg)
                af[kg] = *(const bf16x8*)(w0bf + (size_t)r*4096 + (obase + l31)*64 + kg*16 + kh*8);
            #pragma unroll
            for (int kg = 0; kg < 4; ++kg){
                int cb = kg*32 + kh*16;
                int p0_ = pxb + l31 + dx + 1;
                bf16x8 b0_ = *(const bf16x8*)((char*)Xs + rr*16640 + p0_*128 + (cb ^ ((p0_ & 7) << 4)));
                acc0 = __builtin_amdgcn_mfma_f32_32x32x16_bf16(af[kg], b0_, acc0, 0, 0, 0);
                int p1_ = p0_ + 32;
                bf16x8 b1_ = *(const bf16x8*)((char*)Xs + rr*16640 + p1_*128 + (cb ^ ((p1_ & 7) << 4)));
                acc1 = __builtin_amdgcn_mfma_f32_32x32x16_bf16(af[kg], b1_, acc1, 0, 0, 0);
            }
        }
        #pragma unroll
        for (int reg = 0; reg < 16; ++reg){
            int o = obase + (reg & 3) + 8*(reg >> 2) + 4*kh;
            float s = g0[o] * rsqrtf(v0[o] + EPSV);
            float bi = b0[o] - m0[o]*s;
            int j = j0h + pxb + l31;
            out[((size_t)(b*192 + o))*HW + i*TS + j]      = silu_f(acc0[reg]*s + bi);
            out[((size_t)(b*192 + o))*HW + i*TS + j + 32] = silu_f(acc1[reg]*s + bi);
        }
    } else {
        int idx = (blk - 2048)*256 + tid;
        int px = idx & 65535;
        int t2 = idx >> 16;
        int b = t2 & 3;
        int o6 = t2 >> 2;
        float s_ = 0.f;
        #pragma unroll
        for (int chunk = 0; chunk < 8; ++chunk)
            s_ += poff[((size_t)((chunk*4 + o6)*4 + b))*HW + px];
        int morph = o6 >> 1;
        int ch = (o6==0)?0:(o6==1)?2:(o6==2)?3:5;
        const float* og_ = morph? ogy:ogx; const float* ov_ = morph? ovy:ovx;
        const float* ob_ = morph? oby:obx; const float* om_ = morph? omy:omx;
        const float* obb_ = morph? obby:obbx;
        float sc = og_[ch]*rsqrtf(ov_[ch]+EPSV);
        float bi = (ob_[ch]-om_[ch])*sc + obb_[ch];
        int pl = (o6 & 1)*2;
        float* dst = (morph? off1:off0) + ((size_t)(b*3+pl))*HW;
        dst[px] = tanhf(s_*sc + bi);
    }
}

// ---------------- DSC both morphs: LDS-staged local window gather -> LDS bf16 -> MFMA ----------------
__global__ __launch_bounds__(256) void k_dsc2m(const ushort_t* __restrict__ xbf,
        const float* __restrict__ off0, const float* __restrict__ off1,
        const ushort_t* __restrict__ wbfx, const ushort_t* __restrict__ wbfy,
        const float* __restrict__ bwx, const float* __restrict__ bwy,
        ushort_t* __restrict__ zbuf, float* __restrict__ part){
    __shared__ __align__(16) ushort_t Vt[3*64*64];
    __shared__ __align__(16) ushort_t Xg[7][4][64];
    int mz = blockIdx.z;
    int b = mz & 3;
    int morph = mz >> 2;
    int i = blockIdx.y;
    int j0 = blockIdx.x * 64;
    int tid = threadIdx.x;
    int lane16 = tid & 15;
    int pq = tid >> 4;
    const float fi = (float)i;
    const float* offm = morph ? off1 : off0;

    if (morph == 0){
        int vec = tid >> 4;       // 0..15
        int s = vec >> 2, cs = vec & 3;
        int row = min(max(i - 1 + s, 0), 255);
        int col = min(max(i - 2 + cs, 0), 255);
        int chunk = lane16 >> 1, off8 = (lane16 & 1)*4;
        *(u16x4*)&Xg[s][cs][lane16*4] =
            *(const u16x4*)(xbf + (((size_t)chunk*258 + row + 1)*XPITCH + 1 + col)*8 + off8);
    } else {
        if (tid < 112){
            int s = tid >> 4;     // 0..6
            int row = min(max(i - 3 + s, 0), 255);
            int chunk = lane16 >> 1, off8 = (lane16 & 1)*4;
            *(u16x4*)&Xg[s][0][lane16*4] =
                *(const u16x4*)(xbf + (((size_t)chunk*258 + row + 1)*XPITCH + 1 + i)*8 + off8);
        }
    }
    __syncthreads();

    #pragma unroll
    for (int it = 0; it < 12; ++it){
        int pair = it*16 + pq;
        int t = pair >> 6, jloc = pair & 63;
        float y, wx1, wx0;
        int x0i, x1i;
        if (morph == 0){
            int j = j0 + jloc;
            float off = (t == 1) ? 0.f : offm[((size_t)(b*3 + t)*TS + i)*TS + j];
            y = fi + off;
            float vp = (t==0) ? -2.0f : ((t==1) ? -0.5f : 1.0f);
            float xf = fi + vp;
            float x0 = fminf(fmaxf(floorf(xf), 0.f), 255.f);
            float x1 = fminf(fmaxf(floorf(xf) + 1.f, 0.f), 255.f);
            wx1 = x1 - xf; wx0 = xf - x0;
            x0i = (int)x0; x1i = (int)x1;
        } else {
            int q = 3*(j0 + jloc) + t;
            int dl = q >> 8, jj = q & 255;
            float off = (dl == 1) ? 0.f : offm[((size_t)(b*3 + dl)*TS + i)*TS + jj];
            float vp = (dl==0) ? -2.0f : ((dl==1) ? -0.5f : 1.0f);
            y = fi + vp + off;
            wx1 = (i < 255) ? 1.f : 0.f; wx0 = 0.f;
            x0i = i; x1i = i;
        }
        float yf = floorf(y);
        float y0 = fminf(fmaxf(yf, 0.f), 255.f);
        float y1 = fminf(fmaxf(yf + 1.f, 0.f), 255.f);
        float wy1 = y1 - y, wy0 = y - y0;
        int y0i = (int)y0, y1i = (int)y1;
        int c0 = lane16*4;
        int rbase = morph ? (i - 3) : (i - 1);
        int rs0 = y0i - rbase;
        int rs1 = y1i - rbase;
        int cs0 = morph ? 0 : (x0i - (i - 2));
        u16x4 a  = *(const u16x4*)&Xg[rs0][cs0][c0];
        u16x4 c_ = *(const u16x4*)&Xg[rs1][cs0][c0];
        float v[4];
        if (morph == 0 && wx0 != 0.f){
            int cs1 = x1i - (i - 2);
            u16x4 bv = *(const u16x4*)&Xg[rs0][cs1][c0];
            u16x4 d  = *(const u16x4*)&Xg[rs1][cs1][c0];
            #pragma unroll
            for (int k = 0; k < 4; ++k)
                v[k] = wy1*(wx1*bf2f(a[k]) + wx0*bf2f(bv[k]))
                     + wy0*(wx1*bf2f(c_[k]) + wx0*bf2f(d[k]));
        } else {
            #pragma unroll
            for (int k = 0; k < 4; ++k)
                v[k] = wx1*(wy1*bf2f(a[k]) + wy0*bf2f(c_[k]));
        }
        unsigned int lo = (unsigned int)f2bf(v[0]) | ((unsigned int)f2bf(v[1]) << 16);
        unsigned int hi = (unsigned int)f2bf(v[2]) | ((unsigned int)f2bf(v[3]) << 16);
        int cbyte = (c0*2) ^ ((jloc & 7) << 4);
        uint2 pk; pk.x = lo; pk.y = hi;
        *(uint2*)((char*)Vt + t*8192 + jloc*128 + cbyte) = pk;
    }
    __syncthreads();

    const ushort_t* wbf = morph ? wbfy : wbfx;
    const float* wb = morph ? bwy : bwx;
    ushort_t* zb = zbuf + (size_t)morph*4*64*HW;

    int wv = tid >> 6;
    int lane = tid & 63;
    int l15 = lane & 15, lhi = lane >> 4;
    int mi = wv;
    f32x4 acc[4];
    #pragma unroll
    for (int ni = 0; ni < 4; ++ni) acc[ni] = (f32x4){0.f,0.f,0.f,0.f};
    bf16x8 af[6];
    #pragma unroll
    for (int ks = 0; ks < 6; ++ks)
        af[ks] = *(const bf16x8*)(wbf + (mi*16 + l15)*192 + ks*32 + lhi*8);
    #pragma unroll
    for (int ks = 0; ks < 6; ++ks){
        int t = ks >> 1;
        int cbyte = ((ks & 1)*32 + lhi*8)*2;
        #pragma unroll
        for (int ni = 0; ni < 4; ++ni){
            int j = ni*16 + l15;
            bf16x8 bfr = *(const bf16x8*)((char*)Vt + t*8192 + j*128 + (cbyte ^ ((j & 7) << 4)));
            acc[ni] = __builtin_amdgcn_mfma_f32_16x16x32_bf16(af[ks], bfr, acc[ni], 0, 0, 0);
        }
    }
    float rsum[4], rsq[4];
    #pragma unroll
    for (int reg = 0; reg < 4; ++reg){
        int o = mi*16 + lhi*4 + reg;
        float bias = wb[o];
        float rs = 0.f, rq = 0.f;
        #pragma unroll
        for (int ni = 0; ni < 4; ++ni){
            int j = j0 + ni*16 + l15;
            float val = acc[ni][reg] + bias;
            zb[((size_t)b*64 + o)*HW + i*TS + j] = f2bf(val);
            rs += val; rq += val*val;
        }
        #pragma unroll
        for (int m = 1; m < 16; m <<= 1){
            rs += __shfl_xor(rs, m, 64);
            rq += __shfl_xor(rq, m, 64);
        }
        rsum[reg] = rs; rsq[reg] = rq;
    }
    if (l15 == 0){
        float ts = rsum[0]+rsum[1]+rsum[2]+rsum[3];
        float tq = rsq[0]+rsq[1]+rsq[2]+rsq[3];
        int g = mi*4 + lhi;
        size_t slot = (((size_t)(morph*4 + b)*16 + g)*1024) + (blockIdx.y*4 + blockIdx.x);
        part[slot*2]   = ts;
        part[slot*2+1] = tq;
    }
}

// ---------------- GN final: reduce 1024 partials per (m,b,g) ----------------
__global__ __launch_bounds__(256) void k_gnfinal2(const float* __restrict__ part, float* __restrict__ stats){
    int slot = blockIdx.x;
    float s = 0.f, q = 0.f;
    for (int k = threadIdx.x; k < 1024; k += 256){
        s += part[((size_t)slot*1024 + k)*2];
        q += part[((size_t)slot*1024 + k)*2 + 1];
    }
    #pragma unroll
    for (int d = 32; d > 0; d >>= 1){ s += __shfl_down(s, d, 64); q += __shfl_down(q, d, 64); }
    __shared__ float rs[4], rq[4];
    int lane = threadIdx.x & 63, wv = threadIdx.x >> 6;
    if (lane == 0){ rs[wv] = s; rq[wv] = q; }
    __syncthreads();
    if (threadIdx.x == 0){
        float S = rs[0]+rs[1]+rs[2]+rs[3];
        float Q = rq[0]+rq[1]+rq[2]+rq[3];
        float inv = 1.f/262144.f;
        float mean = S*inv;
        float var = Q*inv - mean*mean;
        stats[slot*2] = mean;
        stats[slot*2+1] = rsqrtf(var + EPSV);
    }
}

// ---------------- GN apply: read bf16 z, write f32 out (both morphs) ----------------
__global__ __launch_bounds__(256) void k_gnapply(float* __restrict__ dout, const ushort_t* __restrict__ zb,
        const float* __restrict__ stats,
        const float* __restrict__ ggx, const float* __restrict__ gbx,
        const float* __restrict__ ggy, const float* __restrict__ gby){
    int idx = blockIdx.x*256 + threadIdx.x;
    int pix4 = idx & 16383;
    int chb = idx >> 14;
    int ch = chb & 127;
    int b = chb >> 7;
    int m = ch >> 6;
    int cc = ch & 63;
    int g = cc >> 2;
    const float* gg = m ? ggy : ggx;
    const float* gb = m ? gby : gbx;
    int si = ((m*4 + b)*16 + g)*2;
    float mean = stats[si], rsig = stats[si+1];
    float sc = rsig * gg[cc];
    float bi = gb[cc] - mean*sc;
    u16x4 zv = *(const u16x4*)(zb + (((size_t)(m*4 + b)*64 + cc)*HW) + (size_t)pix4*4);
    float4 v;
    v.x = silu_f(bf2f(zv[0])*sc + bi);
    v.y = silu_f(bf2f(zv[1])*sc + bi);
    v.z = silu_f(bf2f(zv[2])*sc + bi);
    v.w = silu_f(bf2f(zv[3])*sc + bi);
    float4* ptr = (float4*)(dout + ((size_t)(b*192 + 64 + ch))*HW) + pix4;
    *ptr = v;
}

extern "C" void kernel_launch(void* const* d_in, const int* in_sizes, int n_in,
                              void* d_out, int out_size, void* d_ws, size_t ws_size,
                              hipStream_t stream){
    const float* x    = (const float*)d_in[0];
    const float* w0   = (const float*)d_in[1];
    const float* g0   = (const float*)d_in[2];
    const float* b0   = (const float*)d_in[3];
    const float* m0   = (const float*)d_in[4];
    const float* v0   = (const float*)d_in[5];
    const float* owx  = (const float*)d_in[6];
    const float* obx  = (const float*)d_in[7];
    const float* ogx  = (const float*)d_in[8];
    const float* obbx = (const float*)d_in[9];
    const float* omx  = (const float*)d_in[10];
    const float* ovx  = (const float*)d_in[11];
    const float* wx   = (const float*)d_in[12];
    const float* bwx  = (const float*)d_in[13];
    const float* ggx  = (const float*)d_in[14];
    const float* gbx  = (const float*)d_in[15];
    const float* owy  = (const float*)d_in[16];
    const float* oby  = (const float*)d_in[17];
    const float* ogy  = (const float*)d_in[18];
    const float* obby = (const float*)d_in[19];
    const float* omy  = (const float*)d_in[20];
    const float* ovy  = (const float*)d_in[21];
    const float* wy   = (const float*)d_in[22];
    const float* bwy  = (const float*)d_in[23];
    const float* ggy  = (const float*)d_in[24];
    const float* gby  = (const float*)d_in[25];

    float* out = (float*)d_out;
    // ws layout (bytes):
    //   xbf   @ 0          : 34,080,768   (32 planes x 258 x 258 x 8 x 2)
    //   w0bf  @ 34,080,768 : 73,728
    //   wbfx  @ 34,154,496 : 24,576
    //   wbfy  @ 34,179,072 : 24,576
    //   off0  @ 34,203,648 : 3,145,728
    //   off1  @ 37,349,376 : 3,145,728
    //   poff  @ 40,495,104 : 33,554,432   (dead after k_mid)
    //   zbuf  @ 40,495,104 : 67,108,864   (aliases poff)
    //   part  @ 107,603,968: 1,048,576
    //   stats @ 108,652,544: 1,024
    ushort_t* xbf  = (ushort_t*)d_ws;
    ushort_t* w0bf = (ushort_t*)((char*)d_ws + 34080768);
    ushort_t* wbfx = (ushort_t*)((char*)d_ws + 34154496);
    ushort_t* wbfy = (ushort_t*)((char*)d_ws + 34179072);
    float* off0  = (float*)((char*)d_ws + 34203648);
    float* off1  = (float*)((char*)d_ws + 37349376);
    float* poff  = (float*)((char*)d_ws + 40495104);
    ushort_t* zbuf = (ushort_t*)((char*)d_ws + 40495104);
    float* part  = (float*)((char*)d_ws + 107603968);
    float* stats = (float*)((char*)d_ws + 108652544);
    (void)ws_size;

    // fused offp + x->bf16 + halos (4096 + 257 blocks)
    k_pre<<<4353, 256, 0, stream>>>(x, owx, owy, poff, xbf);
    k_wpack<<<240, 256, 0, stream>>>(w0, wx, wy, w0bf, wbfx, wbfy);
    // conv0 | offred (2048 + 4096 blocks)
    k_mid<<<6144, 256, 0, stream>>>(xbf, w0bf, g0, b0, m0, v0, poff,
        ogx, ovx, obx, omx, obbx,
        ogy, ovy, oby, omy, obby,
        off0, off1, out);
    k_dsc2m<<<dim3(4,256,8), 256, 0, stream>>>(xbf, off0, off1, wbfx, wbfy, bwx, bwy, zbuf, part);
    k_gnfinal2<<<128, 256, 0, stream>>>(part, stats);
    k_gnapply<<<32768, 256, 0, stream>>>(out, zbuf, stats, ggx, gbx, ggy, gby);
}

// Round 21
// 262.279 us; speedup vs baseline: 1.0500x; 1.0211x over previous
//
#include <hip/hip_runtime.h>
#include <hip/hip_bf16.h>
#include <math.h>

#define TS 256
#define HW 65536
#define CIN 64
#define EPSV 1e-5f
#define XPITCH 258   // padded row width (cols -1..256); rows padded too (i = -1..256)
// xbf layout (row-major, r18): (((b*258 + row)*XPITCH) + col)*64 + c

typedef __attribute__((ext_vector_type(8))) short bf16x8;
typedef __attribute__((ext_vector_type(4))) float f32x4;
typedef __attribute__((ext_vector_type(16))) float f32x16;
typedef __attribute__((ext_vector_type(4))) unsigned short u16x4;
typedef unsigned short ushort_t;

__device__ __forceinline__ float silu_f(float v){ return v / (1.0f + expf(-v)); }
__device__ __forceinline__ ushort_t f2bf(float f){
    __hip_bfloat16 h = __float2bfloat16(f);
    return *reinterpret_cast<ushort_t*>(&h);
}
__device__ __forceinline__ float bf2f(ushort_t u){
    unsigned int t = ((unsigned int)u) << 16;
    return __uint_as_float(t);
}

// ======== k_A: {offp (0..4095)} | {xbf convert + halos (4096..8448)} | {wpack (8449..8688)} ========
// Each role is byte-for-byte the r18 kernel body; only the block-range dispatch is new.
__global__ __launch_bounds__(256) void k_A(const float* __restrict__ x,
        const float* __restrict__ owx, const float* __restrict__ owy,
        const float* __restrict__ w0, const float* __restrict__ wx, const float* __restrict__ wy,
        float* __restrict__ poff, ushort_t* __restrict__ xbf,
        ushort_t* __restrict__ w0bf, ushort_t* __restrict__ wbfx, ushort_t* __restrict__ wbfy){
    __shared__ __align__(16) char smemA[34176];
    int blk = blockIdx.x;
    int tid = threadIdx.x;
    if (blk < 4096){
        // ---- offp role (r14/r18 verbatim; by = blk>>7, i0 = (blk&127)*2) ----
        float (*xs)[4][258] = (float(*)[4][258])smemA;            // [8][4][258] = 33,024 B
        float (*wsm)[8][9]  = (float(*)[8][9])(smemA + 33024);    // [4][8][9]  = 1,152 B
        int by = blk >> 7;            // b*8 + chunk
        int b = by >> 3, chunk = by & 7;
        int i0 = (blk & 127) * 2;
        for (int idx = tid; idx < 4*8*9; idx += 256){
            int o = idx / 72;
            int rem = idx - o*72;
            int c = rem / 9, tap = rem - c*9;
            int morph = o >> 1;
            int ch = (o==0)?0:(o==1)?2:(o==2)?3:5;
            const float* w = morph ? owy : owx;
            wsm[o][c][tap] = w[(ch*64 + chunk*8 + c)*9 + tap];
        }
        for (int idx = tid; idx < 8*4*258; idx += 256){
            int c = idx / 1032;
            int rem = idx - c*1032;
            int rr = rem / 258, col = rem - rr*258;
            int gy = i0 + rr - 1, gx = col - 1;
            float v = 0.f;
            if (gy >= 0 && gy < 256 && gx >= 0 && gx < 256)
                v = x[((size_t)(b*64 + chunk*8 + c))*HW + gy*256 + gx];
            xs[c][rr][col] = v;
        }
        __syncthreads();
        float acc[4][2];
        #pragma unroll
        for (int o = 0; o < 4; ++o){ acc[o][0]=0.f; acc[o][1]=0.f; }
        int j = tid;
        #pragma unroll
        for (int c = 0; c < 8; ++c){
            float vrow[4][3];
            #pragma unroll
            for (int rr = 0; rr < 4; ++rr){
                vrow[rr][0] = xs[c][rr][j];
                vrow[rr][1] = xs[c][rr][j+1];
                vrow[rr][2] = xs[c][rr][j+2];
            }
            #pragma unroll
            for (int o = 0; o < 4; ++o){
                const float* wr = wsm[o][c];
                #pragma unroll
                for (int ky = 0; ky < 3; ++ky){
                    #pragma unroll
                    for (int kx = 0; kx < 3; ++kx){
                        float wv = wr[ky*3+kx];
                        acc[o][0] += wv * vrow[ky][kx];
                        acc[o][1] += wv * vrow[ky+1][kx];
                    }
                }
            }
        }
        #pragma unroll
        for (int o = 0; o < 4; ++o){
            size_t base = ((size_t)((chunk*4 + o)*4 + b))*HW;
            poff[base + (size_t)i0*256 + j]     = acc[o][0];
            poff[base + (size_t)(i0+1)*256 + j] = acc[o][1];
        }
    } else if (blk < 8449){
        int xb = blk - 4096;
        if (xb < 4096){
            // ---- xbf main role (r18 verbatim) ----
            float (*tile)[65] = (float(*)[65])smemA;   // [64][65] = 16,640 B
            int b = xb >> 10;
            int chunk = xb & 1023;
            int p0 = chunk * 64;
            int i = p0 >> 8, jb = p0 & 255;
            int lane = tid & 63, grp = tid >> 6;
            #pragma unroll
            for (int k = 0; k < 16; ++k){
                int c = k*4 + grp;
                tile[lane][c] = x[((size_t)(b*CIN + c))*HW + p0 + lane];
            }
            __syncthreads();
            #pragma unroll
            for (int k = 0; k < 16; ++k){
                int pp = k*4 + grp;
                xbf[(((size_t)b*258 + (i+1))*XPITCH + 1 + jb + pp)*64 + lane] = f2bf(tile[pp][lane]);
            }
        } else {
            // ---- halo zeroing role (r18 verbatim) ----
            int base = (xb - 4096) * 1024;
            #pragma unroll
            for (int k = 0; k < 4; ++k){
                int h = base + k*256 + tid;
                if (h < 132096){
                    int b = h / 33024;
                    int rem = h - b*33024;
                    int r = (rem >= 16512) ? 257 : 0;
                    int e = (rem >= 16512) ? rem - 16512 : rem;
                    xbf[((size_t)b*258 + r)*XPITCH*64 + e] = 0;
                } else if (h < 263168){
                    int h2 = h - 132096;
                    int b = h2 >> 15;
                    int rem = h2 & 32767;
                    int row = rem >> 7;
                    int rem2 = rem & 127;
                    int colsel = rem2 >> 6;
                    int c = rem2 & 63;
                    xbf[(((size_t)b*258 + row + 1)*XPITCH + (colsel ? 257 : 0))*64 + c] = 0;
                }
            }
        }
    } else {
        // ---- wpack role (r18 verbatim) ----
        int idx = (blk - 8449)*256 + tid;   // 0..61439
        if (idx < 36864){
            int r = idx >> 12;
            int rem = idx & 4095;
            int o = rem >> 6, c = rem & 63;
            w0bf[idx] = f2bf(w0[(o*64 + c)*9 + r]);
        } else {
            int k2 = idx - 36864;
            int set = k2 / 12288;
            int rem = k2 - set*12288;
            int o = rem / 192;
            int k = rem - o*192;
            int t = k >> 6, c = k & 63;
            const float* w = set ? wy : wx;
            ushort_t* dst = set ? wbfy : wbfx;
            dst[rem] = f2bf(w[(o*64 + c)*3 + t]);
        }
    }
}

// ================= k_mid: {conv0 32x32 MFMA (0..2047)} | {offred (2048..6143), planes 0,2 only} =================
__global__ __launch_bounds__(256) void k_mid(
        const ushort_t* __restrict__ xbf, const ushort_t* __restrict__ w0bf,
        const float* __restrict__ g0, const float* __restrict__ b0,
        const float* __restrict__ m0, const float* __restrict__ v0,
        const float* __restrict__ poff,
        const float* __restrict__ ogx, const float* __restrict__ ovx,
        const float* __restrict__ obx, const float* __restrict__ omx,
        const float* __restrict__ obbx,
        const float* __restrict__ ogy, const float* __restrict__ ovy,
        const float* __restrict__ oby, const float* __restrict__ omy,
        const float* __restrict__ obby,
        float* __restrict__ off0, float* __restrict__ off1,
        float* __restrict__ out){
    __shared__ __align__(16) ushort_t Xs[3*130*64];
    int blk = blockIdx.x;
    int tid = threadIdx.x;
    if (blk < 2048){
        int id2 = ((blk & 7) << 8) + (blk >> 3);
        int b  = id2 >> 9;
        int i  = (id2 >> 1) & 255;
        int jh = id2 & 1;
        int j0h = jh*128;
        int wv = tid >> 6;
        int lane = tid & 63;
        int l31 = lane & 31;
        int kh = lane >> 5;
        int obase = (wv & 1) * 32;
        int pxb = (wv >> 1) * 64;

        for (int idx = tid; idx < 3120; idx += 256){
            int rr = idx / 1040;
            int rem = idx - rr*1040;
            int p = rem >> 3, cgrp = rem & 7;
            bf16x8 v = *(const bf16x8*)(xbf + (((size_t)b*258 + (i + rr))*XPITCH + j0h + p)*64 + cgrp*8);
            int byte = rr*16640 + p*128 + ((cgrp*16) ^ ((p & 7) << 4));
            *(bf16x8*)((char*)Xs + byte) = v;
        }
        __syncthreads();

        f32x16 acc0, acc1;
        #pragma unroll
        for (int e = 0; e < 16; ++e){ acc0[e] = 0.f; acc1[e] = 0.f; }

        #pragma unroll
        for (int r = 0; r < 9; ++r){
            const int rr = r/3, dx = r%3 - 1;
            bf16x8 af[4];
            #pragma unroll
            for (int kg = 0; kg < 4; ++kg)
                af[kg] = *(const bf16x8*)(w0bf + (size_t)r*4096 + (obase + l31)*64 + kg*16 + kh*8);
            #pragma unroll
            for (int kg = 0; kg < 4; ++kg){
                int cb = kg*32 + kh*16;
                int p0_ = pxb + l31 + dx + 1;
                bf16x8 b0_ = *(const bf16x8*)((char*)Xs + rr*16640 + p0_*128 + (cb ^ ((p0_ & 7) << 4)));
                acc0 = __builtin_amdgcn_mfma_f32_32x32x16_bf16(af[kg], b0_, acc0, 0, 0, 0);
                int p1_ = p0_ + 32;
                bf16x8 b1_ = *(const bf16x8*)((char*)Xs + rr*16640 + p1_*128 + (cb ^ ((p1_ & 7) << 4)));
                acc1 = __builtin_amdgcn_mfma_f32_32x32x16_bf16(af[kg], b1_, acc1, 0, 0, 0);
            }
        }
        #pragma unroll
        for (int reg = 0; reg < 16; ++reg){
            int o = obase + (reg & 3) + 8*(reg >> 2) + 4*kh;
            float s = g0[o] * rsqrtf(v0[o] + EPSV);
            float bi = b0[o] - m0[o]*s;
            int j = j0h + pxb + l31;
            out[((size_t)(b*192 + o))*HW + i*TS + j]      = silu_f(acc0[reg]*s + bi);
            out[((size_t)(b*192 + o))*HW + i*TS + j + 32] = silu_f(acc1[reg]*s + bi);
        }
    } else {
        int idx = (blk - 2048)*256 + tid;
        int px = idx & 65535;
        int t2 = idx >> 16;
        int b = t2 & 3;
        int o6 = t2 >> 2;
        float s_ = 0.f;
        #pragma unroll
        for (int chunk = 0; chunk < 8; ++chunk)
            s_ += poff[((size_t)((chunk*4 + o6)*4 + b))*HW + px];
        int morph = o6 >> 1;
        int ch = (o6==0)?0:(o6==1)?2:(o6==2)?3:5;
        const float* og_ = morph? ogy:ogx; const float* ov_ = morph? ovy:ovx;
        const float* ob_ = morph? oby:obx; const float* om_ = morph? omy:omx;
        const float* obb_ = morph? obby:obbx;
        float sc = og_[ch]*rsqrtf(ov_[ch]+EPSV);
        float bi = (ob_[ch]-om_[ch])*sc + obb_[ch];
        int pl = (o6 & 1)*2;
        float* dst = (morph? off1:off0) + ((size_t)(b*3+pl))*HW;
        dst[px] = tanhf(s_*sc + bi);
    }
}

// ---------------- DSC both morphs: LDS-staged local window gather -> LDS bf16 -> MFMA ----------------
__global__ __launch_bounds__(256) void k_dsc2m(const ushort_t* __restrict__ xbf,
        const float* __restrict__ off0, const float* __restrict__ off1,
        const ushort_t* __restrict__ wbfx, const ushort_t* __restrict__ wbfy,
        const float* __restrict__ bwx, const float* __restrict__ bwy,
        ushort_t* __restrict__ zbuf, float* __restrict__ part){
    __shared__ __align__(16) ushort_t Vt[3*64*64];
    __shared__ __align__(16) ushort_t Xg[7][4][64];
    int mz = blockIdx.z;
    int b = mz & 3;
    int morph = mz >> 2;
    int i = blockIdx.y;
    int j0 = blockIdx.x * 64;
    int tid = threadIdx.x;
    int lane16 = tid & 15;
    int pq = tid >> 4;
    const float fi = (float)i;
    const float* offm = morph ? off1 : off0;

    if (morph == 0){
        int vec = tid >> 4;       // 0..15
        int s = vec >> 2, cs = vec & 3;
        int row = min(max(i - 1 + s, 0), 255);
        int col = min(max(i - 2 + cs, 0), 255);
        *(u16x4*)&Xg[s][cs][lane16*4] =
            *(const u16x4*)(xbf + ((size_t)(row+1)*XPITCH + 1 + col)*64 + lane16*4);
    } else {
        if (tid < 112){
            int s = tid >> 4;     // 0..6
            int row = min(max(i - 3 + s, 0), 255);
            *(u16x4*)&Xg[s][0][lane16*4] =
                *(const u16x4*)(xbf + ((size_t)(row+1)*XPITCH + 1 + i)*64 + lane16*4);
        }
    }
    __syncthreads();

    #pragma unroll
    for (int it = 0; it < 12; ++it){
        int pair = it*16 + pq;
        int t = pair >> 6, jloc = pair & 63;
        float y, wx1, wx0;
        int x0i, x1i;
        if (morph == 0){
            int j = j0 + jloc;
            float off = (t == 1) ? 0.f : offm[((size_t)(b*3 + t)*TS + i)*TS + j];
            y = fi + off;
            float vp = (t==0) ? -2.0f : ((t==1) ? -0.5f : 1.0f);
            float xf = fi + vp;
            float x0 = fminf(fmaxf(floorf(xf), 0.f), 255.f);
            float x1 = fminf(fmaxf(floorf(xf) + 1.f, 0.f), 255.f);
            wx1 = x1 - xf; wx0 = xf - x0;
            x0i = (int)x0; x1i = (int)x1;
        } else {
            int q = 3*(j0 + jloc) + t;
            int dl = q >> 8, jj = q & 255;
            float off = (dl == 1) ? 0.f : offm[((size_t)(b*3 + dl)*TS + i)*TS + jj];
            float vp = (dl==0) ? -2.0f : ((dl==1) ? -0.5f : 1.0f);
            y = fi + vp + off;
            wx1 = (i < 255) ? 1.f : 0.f; wx0 = 0.f;
            x0i = i; x1i = i;
        }
        float yf = floorf(y);
        float y0 = fminf(fmaxf(yf, 0.f), 255.f);
        float y1 = fminf(fmaxf(yf + 1.f, 0.f), 255.f);
        float wy1 = y1 - y, wy0 = y - y0;
        int y0i = (int)y0, y1i = (int)y1;
        int c0 = lane16*4;
        int rbase = morph ? (i - 3) : (i - 1);
        int rs0 = y0i - rbase;
        int rs1 = y1i - rbase;
        int cs0 = morph ? 0 : (x0i - (i - 2));
        u16x4 a  = *(const u16x4*)&Xg[rs0][cs0][c0];
        u16x4 c_ = *(const u16x4*)&Xg[rs1][cs0][c0];
        float v[4];
        if (morph == 0 && wx0 != 0.f){
            int cs1 = x1i - (i - 2);
            u16x4 bv = *(const u16x4*)&Xg[rs0][cs1][c0];
            u16x4 d  = *(const u16x4*)&Xg[rs1][cs1][c0];
            #pragma unroll
            for (int k = 0; k < 4; ++k)
                v[k] = wy1*(wx1*bf2f(a[k]) + wx0*bf2f(bv[k]))
                     + wy0*(wx1*bf2f(c_[k]) + wx0*bf2f(d[k]));
        } else {
            #pragma unroll
            for (int k = 0; k < 4; ++k)
                v[k] = wx1*(wy1*bf2f(a[k]) + wy0*bf2f(c_[k]));
        }
        unsigned int lo = (unsigned int)f2bf(v[0]) | ((unsigned int)f2bf(v[1]) << 16);
        unsigned int hi = (unsigned int)f2bf(v[2]) | ((unsigned int)f2bf(v[3]) << 16);
        int cbyte = (c0*2) ^ ((jloc & 7) << 4);
        uint2 pk; pk.x = lo; pk.y = hi;
        *(uint2*)((char*)Vt + t*8192 + jloc*128 + cbyte) = pk;
    }
    __syncthreads();

    const ushort_t* wbf = morph ? wbfy : wbfx;
    const float* wb = morph ? bwy : bwx;
    ushort_t* zb = zbuf + (size_t)morph*4*64*HW;

    int wv = tid >> 6;
    int lane = tid & 63;
    int l15 = lane & 15, lhi = lane >> 4;
    int mi = wv;
    f32x4 acc[4];
    #pragma unroll
    for (int ni = 0; ni < 4; ++ni) acc[ni] = (f32x4){0.f,0.f,0.f,0.f};
    bf16x8 af[6];
    #pragma unroll
    for (int ks = 0; ks < 6; ++ks)
        af[ks] = *(const bf16x8*)(wbf + (mi*16 + l15)*192 + ks*32 + lhi*8);
    #pragma unroll
    for (int ks = 0; ks < 6; ++ks){
        int t = ks >> 1;
        int cbyte = ((ks & 1)*32 + lhi*8)*2;
        #pragma unroll
        for (int ni = 0; ni < 4; ++ni){
            int j = ni*16 + l15;
            bf16x8 bfr = *(const bf16x8*)((char*)Vt + t*8192 + j*128 + (cbyte ^ ((j & 7) << 4)));
            acc[ni] = __builtin_amdgcn_mfma_f32_16x16x32_bf16(af[ks], bfr, acc[ni], 0, 0, 0);
        }
    }
    float rsum[4], rsq[4];
    #pragma unroll
    for (int reg = 0; reg < 4; ++reg){
        int o = mi*16 + lhi*4 + reg;
        float bias = wb[o];
        float rs = 0.f, rq = 0.f;
        #pragma unroll
        for (int ni = 0; ni < 4; ++ni){
            int j = j0 + ni*16 + l15;
            float val = acc[ni][reg] + bias;
            zb[((size_t)b*64 + o)*HW + i*TS + j] = f2bf(val);
            rs += val; rq += val*val;
        }
        #pragma unroll
        for (int m = 1; m < 16; m <<= 1){
            rs += __shfl_xor(rs, m, 64);
            rq += __shfl_xor(rq, m, 64);
        }
        rsum[reg] = rs; rsq[reg] = rq;
    }
    if (l15 == 0){
        float ts = rsum[0]+rsum[1]+rsum[2]+rsum[3];
        float tq = rsq[0]+rsq[1]+rsq[2]+rsq[3];
        int g = mi*4 + lhi;
        size_t slot = (((size_t)(morph*4 + b)*16 + g)*1024) + (blockIdx.y*4 + blockIdx.x);
        part[slot*2]   = ts;
        part[slot*2+1] = tq;
    }
}

// ---------------- GN final: reduce 1024 partials per (m,b,g) ----------------
__global__ __launch_bounds__(256) void k_gnfinal2(const float* __restrict__ part, float* __restrict__ stats){
    int slot = blockIdx.x;
    float s = 0.f, q = 0.f;
    for (int k = threadIdx.x; k < 1024; k += 256){
        s += part[((size_t)slot*1024 + k)*2];
        q += part[((size_t)slot*1024 + k)*2 + 1];
    }
    #pragma unroll
    for (int d = 32; d > 0; d >>= 1){ s += __shfl_down(s, d, 64); q += __shfl_down(q, d, 64); }
    __shared__ float rs[4], rq[4];
    int lane = threadIdx.x & 63, wv = threadIdx.x >> 6;
    if (lane == 0){ rs[wv] = s; rq[wv] = q; }
    __syncthreads();
    if (threadIdx.x == 0){
        float S = rs[0]+rs[1]+rs[2]+rs[3];
        float Q = rq[0]+rq[1]+rq[2]+rq[3];
        float inv = 1.f/262144.f;
        float mean = S*inv;
        float var = Q*inv - mean*mean;
        stats[slot*2] = mean;
        stats[slot*2+1] = rsqrtf(var + EPSV);
    }
}

// ---------------- GN apply: read bf16 z, write f32 out (both morphs) ----------------
__global__ __launch_bounds__(256) void k_gnapply(float* __restrict__ dout, const ushort_t* __restrict__ zb,
        const float* __restrict__ stats,
        const float* __restrict__ ggx, const float* __restrict__ gbx,
        const float* __restrict__ ggy, const float* __restrict__ gby){
    int idx = blockIdx.x*256 + threadIdx.x;
    int pix4 = idx & 16383;
    int chb = idx >> 14;
    int ch = chb & 127;
    int b = chb >> 7;
    int m = ch >> 6;
    int cc = ch & 63;
    int g = cc >> 2;
    const float* gg = m ? ggy : ggx;
    const float* gb = m ? gby : gbx;
    int si = ((m*4 + b)*16 + g)*2;
    float mean = stats[si], rsig = stats[si+1];
    float sc = rsig * gg[cc];
    float bi = gb[cc] - mean*sc;
    u16x4 zv = *(const u16x4*)(zb + (((size_t)(m*4 + b)*64 + cc)*HW) + (size_t)pix4*4);
    float4 v;
    v.x = silu_f(bf2f(zv[0])*sc + bi);
    v.y = silu_f(bf2f(zv[1])*sc + bi);
    v.z = silu_f(bf2f(zv[2])*sc + bi);
    v.w = silu_f(bf2f(zv[3])*sc + bi);
    float4* ptr = (float4*)(dout + ((size_t)(b*192 + 64 + ch))*HW) + pix4;
    *ptr = v;
}

extern "C" void kernel_launch(void* const* d_in, const int* in_sizes, int n_in,
                              void* d_out, int out_size, void* d_ws, size_t ws_size,
                              hipStream_t stream){
    const float* x    = (const float*)d_in[0];
    const float* w0   = (const float*)d_in[1];
    const float* g0   = (const float*)d_in[2];
    const float* b0   = (const float*)d_in[3];
    const float* m0   = (const float*)d_in[4];
    const float* v0   = (const float*)d_in[5];
    const float* owx  = (const float*)d_in[6];
    const float* obx  = (const float*)d_in[7];
    const float* ogx  = (const float*)d_in[8];
    const float* obbx = (const float*)d_in[9];
    const float* omx  = (const float*)d_in[10];
    const float* ovx  = (const float*)d_in[11];
    const float* wx   = (const float*)d_in[12];
    const float* bwx  = (const float*)d_in[13];
    const float* ggx  = (const float*)d_in[14];
    const float* gbx  = (const float*)d_in[15];
    const float* owy  = (const float*)d_in[16];
    const float* oby  = (const float*)d_in[17];
    const float* ogy  = (const float*)d_in[18];
    const float* obby = (const float*)d_in[19];
    const float* omy  = (const float*)d_in[20];
    const float* ovy  = (const float*)d_in[21];
    const float* wy   = (const float*)d_in[22];
    const float* bwy  = (const float*)d_in[23];
    const float* ggy  = (const float*)d_in[24];
    const float* gby  = (const float*)d_in[25];

    float* out = (float*)d_out;
    // ws layout (bytes) — xbf correctly sized (34,080,768 = 4*258*258*64*2); no overlap:
    //   xbf   @ 0          : 34,080,768
    //   w0bf  @ 34,080,768 : 73,728
    //   wbfx  @ 34,154,496 : 24,576
    //   wbfy  @ 34,179,072 : 24,576
    //   off0  @ 34,203,648 : 3,145,728
    //   off1  @ 37,349,376 : 3,145,728
    //   poff  @ 40,495,104 : 33,554,432   (dead after k_mid)
    //   zbuf  @ 40,495,104 : 67,108,864   (aliases poff)
    //   part  @ 107,603,968: 1,048,576
    //   stats @ 108,652,544: 1,024
    ushort_t* xbf  = (ushort_t*)d_ws;
    ushort_t* w0bf = (ushort_t*)((char*)d_ws + 34080768);
    ushort_t* wbfx = (ushort_t*)((char*)d_ws + 34154496);
    ushort_t* wbfy = (ushort_t*)((char*)d_ws + 34179072);
    float* off0  = (float*)((char*)d_ws + 34203648);
    float* off1  = (float*)((char*)d_ws + 37349376);
    float* poff  = (float*)((char*)d_ws + 40495104);
    ushort_t* zbuf = (ushort_t*)((char*)d_ws + 40495104);
    float* part  = (float*)((char*)d_ws + 107603968);
    float* stats = (float*)((char*)d_ws + 108652544);
    (void)ws_size;

    // A: offp | xbf+halos | wpack  (4096 + 4353 + 240 = 8689 blocks)
    k_A<<<8689, 256, 0, stream>>>(x, owx, owy, w0, wx, wy, poff, xbf, w0bf, wbfx, wbfy);
    // B: conv0 | offred (2048 + 4096 blocks)
    k_mid<<<6144, 256, 0, stream>>>(xbf, w0bf, g0, b0, m0, v0, poff,
        ogx, ovx, obx, omx, obbx,
        ogy, ovy, oby, omy, obby,
        off0, off1, out);
    k_dsc2m<<<dim3(4,256,8), 256, 0, stream>>>(xbf, off0, off1, wbfx, wbfy, bwx, bwy, zbuf, part);
    k_gnfinal2<<<128, 256, 0, stream>>>(part, stats);
    k_gnapply<<<32768, 256, 0, stream>>>(out, zbuf, stats, ggx, gbx, ggy, gby);
}

// Round 22
// 253.819 us; speedup vs baseline: 1.0850x; 1.0333x over previous
//
#include <hip/hip_runtime.h>
#include <hip/hip_bf16.h>
#include <math.h>

#define TS 256
#define HW 65536
#define CIN 64
#define EPSV 1e-5f
#define XPITCH 258   // padded row width (cols -1..256); rows padded too (i = -1..256)
// xbf layout (row-major): (((b*258 + row)*XPITCH) + col)*64 + c

typedef __attribute__((ext_vector_type(8))) short bf16x8;
typedef __attribute__((ext_vector_type(4))) float f32x4;
typedef __attribute__((ext_vector_type(16))) float f32x16;
typedef __attribute__((ext_vector_type(4))) unsigned short u16x4;
typedef unsigned short ushort_t;

__device__ __forceinline__ float silu_f(float v){ return v / (1.0f + expf(-v)); }
__device__ __forceinline__ ushort_t f2bf(float f){
    __hip_bfloat16 h = __float2bfloat16(f);
    return *reinterpret_cast<ushort_t*>(&h);
}
__device__ __forceinline__ float bf2f(ushort_t u){
    unsigned int t = ((unsigned int)u) << 16;
    return __uint_as_float(t);
}

// ---------------- x (4,64,256,256) f32 -> xbf (4,258,258,64) bf16; data rows at r=i+1 ----
__global__ __launch_bounds__(256) void k_xbf(const float* __restrict__ x, ushort_t* __restrict__ xbf){
    int blk = blockIdx.x;
    int tid = threadIdx.x;
    if (blk < 4096){
        __shared__ float tile[64][65];
        int b = blk >> 10;
        int chunk = blk & 1023;
        int p0 = chunk * 64;
        int i = p0 >> 8, jb = p0 & 255;
        int lane = tid & 63, grp = tid >> 6;
        #pragma unroll
        for (int k = 0; k < 16; ++k){
            int c = k*4 + grp;
            tile[lane][c] = x[((size_t)(b*CIN + c))*HW + p0 + lane];
        }
        __syncthreads();
        #pragma unroll
        for (int k = 0; k < 16; ++k){
            int pp = k*4 + grp;
            xbf[(((size_t)b*258 + (i+1))*XPITCH + 1 + jb + pp)*64 + lane] = f2bf(tile[pp][lane]);
        }
    } else {
        int base = (blk - 4096) * 1024;
        #pragma unroll
        for (int k = 0; k < 4; ++k){
            int h = base + k*256 + tid;
            if (h < 132096){
                int b = h / 33024;
                int rem = h - b*33024;
                int r = (rem >= 16512) ? 257 : 0;
                int e = (rem >= 16512) ? rem - 16512 : rem;
                xbf[((size_t)b*258 + r)*XPITCH*64 + e] = 0;
            } else if (h < 263168){
                int h2 = h - 132096;
                int b = h2 >> 15;
                int rem = h2 & 32767;
                int row = rem >> 7;
                int rem2 = rem & 127;
                int colsel = rem2 >> 6;
                int c = rem2 & 63;
                xbf[(((size_t)b*258 + row + 1)*XPITCH + (colsel ? 257 : 0))*64 + c] = 0;
            }
        }
    }
}

// ---------------- weight repacks, merged ----
__global__ __launch_bounds__(256) void k_wpack(const float* __restrict__ w0,
        const float* __restrict__ wx, const float* __restrict__ wy,
        ushort_t* __restrict__ w0bf, ushort_t* __restrict__ wbfx, ushort_t* __restrict__ wbfy){
    int idx = blockIdx.x*256 + threadIdx.x;   // 61440 total
    if (idx < 36864){
        int r = idx >> 12;
        int rem = idx & 4095;
        int o = rem >> 6, c = rem & 63;
        w0bf[idx] = f2bf(w0[(o*64 + c)*9 + r]);
    } else {
        int k2 = idx - 36864;   // 0..24575
        int set = k2 / 12288;
        int rem = k2 - set*12288;
        int o = rem / 192;
        int k = rem - o*192;
        int t = k >> 6, c = k & 63;
        const float* w = set ? wy : wx;
        ushort_t* dst = set ? wbfy : wbfx;
        dst[rem] = f2bf(w[(o*64 + c)*3 + t]);
    }
}

// ---------------- offset conv partials: 8-ch chunk, 2 output rows, exact f32 (r14 verbatim) ----------------
__global__ __launch_bounds__(256) void k_offp(const float* __restrict__ x,
        const float* __restrict__ owx, const float* __restrict__ owy,
        float* __restrict__ poff){
    __shared__ float xs[8][4][258];
    __shared__ float wsm[4][8][9];
    int by = blockIdx.y;          // b*8 + chunk
    int b = by >> 3, chunk = by & 7;
    int i0 = blockIdx.x * 2;
    int tid = threadIdx.x;
    for (int idx = tid; idx < 4*8*9; idx += 256){
        int o = idx / 72;
        int rem = idx - o*72;
        int c = rem / 9, tap = rem - c*9;
        int morph = o >> 1;
        int ch = (o==0)?0:(o==1)?2:(o==2)?3:5;
        const float* w = morph ? owy : owx;
        wsm[o][c][tap] = w[(ch*64 + chunk*8 + c)*9 + tap];
    }
    for (int idx = tid; idx < 8*4*258; idx += 256){
        int c = idx / 1032;
        int rem = idx - c*1032;
        int rr = rem / 258, col = rem - rr*258;
        int gy = i0 + rr - 1, gx = col - 1;
        float v = 0.f;
        if (gy >= 0 && gy < 256 && gx >= 0 && gx < 256)
            v = x[((size_t)(b*64 + chunk*8 + c))*HW + gy*256 + gx];
        xs[c][rr][col] = v;
    }
    __syncthreads();
    float acc[4][2];
    #pragma unroll
    for (int o = 0; o < 4; ++o){ acc[o][0]=0.f; acc[o][1]=0.f; }
    int j = tid;
    #pragma unroll
    for (int c = 0; c < 8; ++c){
        float vrow[4][3];
        #pragma unroll
        for (int rr = 0; rr < 4; ++rr){
            vrow[rr][0] = xs[c][rr][j];
            vrow[rr][1] = xs[c][rr][j+1];
            vrow[rr][2] = xs[c][rr][j+2];
        }
        #pragma unroll
        for (int o = 0; o < 4; ++o){
            const float* wr = wsm[o][c];
            #pragma unroll
            for (int ky = 0; ky < 3; ++ky){
                #pragma unroll
                for (int kx = 0; kx < 3; ++kx){
                    float wv = wr[ky*3+kx];
                    acc[o][0] += wv * vrow[ky][kx];
                    acc[o][1] += wv * vrow[ky+1][kx];
                }
            }
        }
    }
    #pragma unroll
    for (int o = 0; o < 4; ++o){
        size_t base = ((size_t)((chunk*4 + o)*4 + b))*HW;
        poff[base + (size_t)i0*256 + j]     = acc[o][0];
        poff[base + (size_t)(i0+1)*256 + j] = acc[o][1];
    }
}

// ================= k_mid: {conv0 2-row x 64-px tile, 32x32 MFMA (0..2047)} | {offred (2048..6143)} =================
__global__ __launch_bounds__(256) void k_mid(
        const ushort_t* __restrict__ xbf, const ushort_t* __restrict__ w0bf,
        const float* __restrict__ g0, const float* __restrict__ b0,
        const float* __restrict__ m0, const float* __restrict__ v0,
        const float* __restrict__ poff,
        const float* __restrict__ ogx, const float* __restrict__ ovx,
        const float* __restrict__ obx, const float* __restrict__ omx,
        const float* __restrict__ obbx,
        const float* __restrict__ ogy, const float* __restrict__ ovy,
        const float* __restrict__ oby, const float* __restrict__ omy,
        const float* __restrict__ obby,
        float* __restrict__ off0, float* __restrict__ off1,
        float* __restrict__ out){
    // Xs: 4 rows x 66 px x 64 ch bf16, byte = rr*8448 + p*128 + ((c*2)^((p&7)<<4)); 33,792 B
    __shared__ __align__(16) ushort_t Xs[4*66*64];
    int blk = blockIdx.x;
    int tid = threadIdx.x;
    if (blk < 2048){
        // ---- conv0 role: block = (b, row-pair, 64-px quarter) ----
        int id2 = ((blk & 7) << 8) + (blk >> 3);   // XCD-banded
        int b  = id2 >> 9;
        int ip = (id2 >> 2) & 127;
        int jq = id2 & 3;
        int i0 = ip*2;
        int j0 = jq*64;
        int wv = tid >> 6;
        int lane = tid & 63;
        int l31 = lane & 31;
        int kh = lane >> 5;
        int row = wv >> 1;            // 0..1
        int obase = (wv & 1) * 32;

        // stage rows i0-1..i0+2 (padded rows i0..i0+3), padded cols j0..j0+65
        for (int idx = tid; idx < 2112; idx += 256){
            int rr = idx / 528;
            int rem = idx - rr*528;
            int p = rem >> 3, cgrp = rem & 7;
            bf16x8 v = *(const bf16x8*)(xbf + (((size_t)b*258 + (i0 + rr))*XPITCH + j0 + p)*64 + cgrp*8);
            int byte = rr*8448 + p*128 + ((cgrp*16) ^ ((p & 7) << 4));
            *(bf16x8*)((char*)Xs + byte) = v;
        }
        __syncthreads();

        bf16x8 af[9][4];
        #pragma unroll
        for (int r = 0; r < 9; ++r)
            #pragma unroll
            for (int kg = 0; kg < 4; ++kg)
                af[r][kg] = *(const bf16x8*)(w0bf + (size_t)r*4096 + (obase + l31)*64 + kg*16 + kh*8);

        f32x16 acc0, acc1;
        #pragma unroll
        for (int e = 0; e < 16; ++e){ acc0[e] = 0.f; acc1[e] = 0.f; }

        #pragma unroll
        for (int r = 0; r < 9; ++r){
            const int rr = row + r/3;     // dy+1 offset within staged window
            const int dx = r%3 - 1;
            #pragma unroll
            for (int kg = 0; kg < 4; ++kg){
                int cb = kg*32 + kh*16;
                int p0_ = l31 + dx + 1;
                bf16x8 b0_ = *(const bf16x8*)((char*)Xs + rr*8448 + p0_*128 + (cb ^ ((p0_ & 7) << 4)));
                acc0 = __builtin_amdgcn_mfma_f32_32x32x16_bf16(af[r][kg], b0_, acc0, 0, 0, 0);
                int p1_ = p0_ + 32;
                bf16x8 b1_ = *(const bf16x8*)((char*)Xs + rr*8448 + p1_*128 + (cb ^ ((p1_ & 7) << 4)));
                acc1 = __builtin_amdgcn_mfma_f32_32x32x16_bf16(af[r][kg], b1_, acc1, 0, 0, 0);
            }
        }
        int i = i0 + row;
        #pragma unroll
        for (int reg = 0; reg < 16; ++reg){
            int o = obase + (reg & 3) + 8*(reg >> 2) + 4*kh;
            float s = g0[o] * rsqrtf(v0[o] + EPSV);
            float bi = b0[o] - m0[o]*s;
            int j = j0 + l31;
            out[((size_t)(b*192 + o))*HW + i*TS + j]      = silu_f(acc0[reg]*s + bi);
            out[((size_t)(b*192 + o))*HW + i*TS + j + 32] = silu_f(acc1[reg]*s + bi);
        }
    } else {
        // ---- offred role: planes 0,2 only ----
        int idx = (blk - 2048)*256 + tid;
        int px = idx & 65535;
        int t2 = idx >> 16;
        int b = t2 & 3;
        int o6 = t2 >> 2;
        float s_ = 0.f;
        #pragma unroll
        for (int chunk = 0; chunk < 8; ++chunk)
            s_ += poff[((size_t)((chunk*4 + o6)*4 + b))*HW + px];
        int morph = o6 >> 1;
        int ch = (o6==0)?0:(o6==1)?2:(o6==2)?3:5;
        const float* og_ = morph? ogy:ogx; const float* ov_ = morph? ovy:ovx;
        const float* ob_ = morph? oby:obx; const float* om_ = morph? omy:omx;
        const float* obb_ = morph? obby:obbx;
        float sc = og_[ch]*rsqrtf(ov_[ch]+EPSV);
        float bi = (ob_[ch]-om_[ch])*sc + obb_[ch];
        int pl = (o6 & 1)*2;
        float* dst = (morph? off1:off0) + ((size_t)(b*3+pl))*HW;
        dst[px] = tanhf(s_*sc + bi);
    }
}

// ---------------- DSC both morphs: LDS-staged local window gather -> LDS bf16 -> MFMA ----------------
__global__ __launch_bounds__(256) void k_dsc2m(const ushort_t* __restrict__ xbf,
        const float* __restrict__ off0, const float* __restrict__ off1,
        const ushort_t* __restrict__ wbfx, const ushort_t* __restrict__ wbfy,
        const float* __restrict__ bwx, const float* __restrict__ bwy,
        ushort_t* __restrict__ zbuf, float* __restrict__ part){
    __shared__ __align__(16) ushort_t Vt[3*64*64];
    __shared__ __align__(16) ushort_t Xg[7][4][64];
    int mz = blockIdx.z;
    int b = mz & 3;
    int morph = mz >> 2;
    int i = blockIdx.y;
    int j0 = blockIdx.x * 64;
    int tid = threadIdx.x;
    int lane16 = tid & 15;
    int pq = tid >> 4;
    const float fi = (float)i;
    const float* offm = morph ? off1 : off0;

    if (morph == 0){
        int vec = tid >> 4;       // 0..15
        int s = vec >> 2, cs = vec & 3;
        int row = min(max(i - 1 + s, 0), 255);
        int col = min(max(i - 2 + cs, 0), 255);
        *(u16x4*)&Xg[s][cs][lane16*4] =
            *(const u16x4*)(xbf + ((size_t)(row+1)*XPITCH + 1 + col)*64 + lane16*4);
    } else {
        if (tid < 112){
            int s = tid >> 4;     // 0..6
            int row = min(max(i - 3 + s, 0), 255);
            *(u16x4*)&Xg[s][0][lane16*4] =
                *(const u16x4*)(xbf + ((size_t)(row+1)*XPITCH + 1 + i)*64 + lane16*4);
        }
    }
    __syncthreads();

    #pragma unroll
    for (int it = 0; it < 12; ++it){
        int pair = it*16 + pq;
        int t = pair >> 6, jloc = pair & 63;
        float y, wx1, wx0;
        int x0i, x1i;
        if (morph == 0){
            int j = j0 + jloc;
            float off = (t == 1) ? 0.f : offm[((size_t)(b*3 + t)*TS + i)*TS + j];
            y = fi + off;
            float vp = (t==0) ? -2.0f : ((t==1) ? -0.5f : 1.0f);
            float xf = fi + vp;
            float x0 = fminf(fmaxf(floorf(xf), 0.f), 255.f);
            float x1 = fminf(fmaxf(floorf(xf) + 1.f, 0.f), 255.f);
            wx1 = x1 - xf; wx0 = xf - x0;
            x0i = (int)x0; x1i = (int)x1;
        } else {
            int q = 3*(j0 + jloc) + t;
            int dl = q >> 8, jj = q & 255;
            float off = (dl == 1) ? 0.f : offm[((size_t)(b*3 + dl)*TS + i)*TS + jj];
            float vp = (dl==0) ? -2.0f : ((dl==1) ? -0.5f : 1.0f);
            y = fi + vp + off;
            wx1 = (i < 255) ? 1.f : 0.f; wx0 = 0.f;
            x0i = i; x1i = i;
        }
        float yf = floorf(y);
        float y0 = fminf(fmaxf(yf, 0.f), 255.f);
        float y1 = fminf(fmaxf(yf + 1.f, 0.f), 255.f);
        float wy1 = y1 - y, wy0 = y - y0;
        int y0i = (int)y0, y1i = (int)y1;
        int c0 = lane16*4;
        int rbase = morph ? (i - 3) : (i - 1);
        int rs0 = y0i - rbase;
        int rs1 = y1i - rbase;
        int cs0 = morph ? 0 : (x0i - (i - 2));
        u16x4 a  = *(const u16x4*)&Xg[rs0][cs0][c0];
        u16x4 c_ = *(const u16x4*)&Xg[rs1][cs0][c0];
        float v[4];
        if (morph == 0 && wx0 != 0.f){
            int cs1 = x1i - (i - 2);
            u16x4 bv = *(const u16x4*)&Xg[rs0][cs1][c0];
            u16x4 d  = *(const u16x4*)&Xg[rs1][cs1][c0];
            #pragma unroll
            for (int k = 0; k < 4; ++k)
                v[k] = wy1*(wx1*bf2f(a[k]) + wx0*bf2f(bv[k]))
                     + wy0*(wx1*bf2f(c_[k]) + wx0*bf2f(d[k]));
        } else {
            #pragma unroll
            for (int k = 0; k < 4; ++k)
                v[k] = wx1*(wy1*bf2f(a[k]) + wy0*bf2f(c_[k]));
        }
        unsigned int lo = (unsigned int)f2bf(v[0]) | ((unsigned int)f2bf(v[1]) << 16);
        unsigned int hi = (unsigned int)f2bf(v[2]) | ((unsigned int)f2bf(v[3]) << 16);
        int cbyte = (c0*2) ^ ((jloc & 7) << 4);
        uint2 pk; pk.x = lo; pk.y = hi;
        *(uint2*)((char*)Vt + t*8192 + jloc*128 + cbyte) = pk;
    }
    __syncthreads();

    const ushort_t* wbf = morph ? wbfy : wbfx;
    const float* wb = morph ? bwy : bwx;
    ushort_t* zb = zbuf + (size_t)morph*4*64*HW;

    int wv = tid >> 6;
    int lane = tid & 63;
    int l15 = lane & 15, lhi = lane >> 4;
    int mi = wv;
    f32x4 acc[4];
    #pragma unroll
    for (int ni = 0; ni < 4; ++ni) acc[ni] = (f32x4){0.f,0.f,0.f,0.f};
    bf16x8 af[6];
    #pragma unroll
    for (int ks = 0; ks < 6; ++ks)
        af[ks] = *(const bf16x8*)(wbf + (mi*16 + l15)*192 + ks*32 + lhi*8);
    #pragma unroll
    for (int ks = 0; ks < 6; ++ks){
        int t = ks >> 1;
        int cbyte = ((ks & 1)*32 + lhi*8)*2;
        #pragma unroll
        for (int ni = 0; ni < 4; ++ni){
            int j = ni*16 + l15;
            bf16x8 bfr = *(const bf16x8*)((char*)Vt + t*8192 + j*128 + (cbyte ^ ((j & 7) << 4)));
            acc[ni] = __builtin_amdgcn_mfma_f32_16x16x32_bf16(af[ks], bfr, acc[ni], 0, 0, 0);
        }
    }
    float rsum[4], rsq[4];
    #pragma unroll
    for (int reg = 0; reg < 4; ++reg){
        int o = mi*16 + lhi*4 + reg;
        float bias = wb[o];
        float rs = 0.f, rq = 0.f;
        #pragma unroll
        for (int ni = 0; ni < 4; ++ni){
            int j = j0 + ni*16 + l15;
            float val = acc[ni][reg] + bias;
            zb[((size_t)b*64 + o)*HW + i*TS + j] = f2bf(val);
            rs += val; rq += val*val;
        }
        #pragma unroll
        for (int m = 1; m < 16; m <<= 1){
            rs += __shfl_xor(rs, m, 64);
            rq += __shfl_xor(rq, m, 64);
        }
        rsum[reg] = rs; rsq[reg] = rq;
    }
    if (l15 == 0){
        float ts = rsum[0]+rsum[1]+rsum[2]+rsum[3];
        float tq = rsq[0]+rsq[1]+rsq[2]+rsq[3];
        int g = mi*4 + lhi;
        size_t slot = (((size_t)(morph*4 + b)*16 + g)*1024) + (blockIdx.y*4 + blockIdx.x);
        part[slot*2]   = ts;
        part[slot*2+1] = tq;
    }
}

// ---------------- GN final: reduce 1024 partials per (m,b,g) ----------------
__global__ __launch_bounds__(256) void k_gnfinal2(const float* __restrict__ part, float* __restrict__ stats){
    int slot = blockIdx.x;
    float s = 0.f, q = 0.f;
    for (int k = threadIdx.x; k < 1024; k += 256){
        s += part[((size_t)slot*1024 + k)*2];
        q += part[((size_t)slot*1024 + k)*2 + 1];
    }
    #pragma unroll
    for (int d = 32; d > 0; d >>= 1){ s += __shfl_down(s, d, 64); q += __shfl_down(q, d, 64); }
    __shared__ float rs[4], rq[4];
    int lane = threadIdx.x & 63, wv = threadIdx.x >> 6;
    if (lane == 0){ rs[wv] = s; rq[wv] = q; }
    __syncthreads();
    if (threadIdx.x == 0){
        float S = rs[0]+rs[1]+rs[2]+rs[3];
        float Q = rq[0]+rq[1]+rq[2]+rq[3];
        float inv = 1.f/262144.f;
        float mean = S*inv;
        float var = Q*inv - mean*mean;
        stats[slot*2] = mean;
        stats[slot*2+1] = rsqrtf(var + EPSV);
    }
}

// ---------------- GN apply: read bf16 z, write f32 out (both morphs) ----------------
__global__ __launch_bounds__(256) void k_gnapply(float* __restrict__ dout, const ushort_t* __restrict__ zb,
        const float* __restrict__ stats,
        const float* __restrict__ ggx, const float* __restrict__ gbx,
        const float* __restrict__ ggy, const float* __restrict__ gby){
    int idx = blockIdx.x*256 + threadIdx.x;
    int pix4 = idx & 16383;
    int chb = idx >> 14;
    int ch = chb & 127;
    int b = chb >> 7;
    int m = ch >> 6;
    int cc = ch & 63;
    int g = cc >> 2;
    const float* gg = m ? ggy : ggx;
    const float* gb = m ? gby : gbx;
    int si = ((m*4 + b)*16 + g)*2;
    float mean = stats[si], rsig = stats[si+1];
    float sc = rsig * gg[cc];
    float bi = gb[cc] - mean*sc;
    u16x4 zv = *(const u16x4*)(zb + (((size_t)(m*4 + b)*64 + cc)*HW) + (size_t)pix4*4);
    float4 v;
    v.x = silu_f(bf2f(zv[0])*sc + bi);
    v.y = silu_f(bf2f(zv[1])*sc + bi);
    v.z = silu_f(bf2f(zv[2])*sc + bi);
    v.w = silu_f(bf2f(zv[3])*sc + bi);
    float4* ptr = (float4*)(dout + ((size_t)(b*192 + 64 + ch))*HW) + pix4;
    *ptr = v;
}

extern "C" void kernel_launch(void* const* d_in, const int* in_sizes, int n_in,
                              void* d_out, int out_size, void* d_ws, size_t ws_size,
                              hipStream_t stream){
    const float* x    = (const float*)d_in[0];
    const float* w0   = (const float*)d_in[1];
    const float* g0   = (const float*)d_in[2];
    const float* b0   = (const float*)d_in[3];
    const float* m0   = (const float*)d_in[4];
    const float* v0   = (const float*)d_in[5];
    const float* owx  = (const float*)d_in[6];
    const float* obx  = (const float*)d_in[7];
    const float* ogx  = (const float*)d_in[8];
    const float* obbx = (const float*)d_in[9];
    const float* omx  = (const float*)d_in[10];
    const float* ovx  = (const float*)d_in[11];
    const float* wx   = (const float*)d_in[12];
    const float* bwx  = (const float*)d_in[13];
    const float* ggx  = (const float*)d_in[14];
    const float* gbx  = (const float*)d_in[15];
    const float* owy  = (const float*)d_in[16];
    const float* oby  = (const float*)d_in[17];
    const float* ogy  = (const float*)d_in[18];
    const float* obby = (const float*)d_in[19];
    const float* omy  = (const float*)d_in[20];
    const float* ovy  = (const float*)d_in[21];
    const float* wy   = (const float*)d_in[22];
    const float* bwy  = (const float*)d_in[23];
    const float* ggy  = (const float*)d_in[24];
    const float* gby  = (const float*)d_in[25];

    float* out = (float*)d_out;
    // ws layout (bytes):
    //   xbf   @ 0          : 34,080,768
    //   w0bf  @ 34,080,768 : 73,728
    //   wbfx  @ 34,154,496 : 24,576
    //   wbfy  @ 34,179,072 : 24,576
    //   off0  @ 34,203,648 : 3,145,728
    //   off1  @ 37,349,376 : 3,145,728
    //   poff  @ 40,495,104 : 33,554,432   (dead after k_mid)
    //   zbuf  @ 40,495,104 : 67,108,864   (aliases poff)
    //   part  @ 107,603,968: 1,048,576
    //   stats @ 108,652,544: 1,024
    ushort_t* xbf  = (ushort_t*)d_ws;
    ushort_t* w0bf = (ushort_t*)((char*)d_ws + 34080768);
    ushort_t* wbfx = (ushort_t*)((char*)d_ws + 34154496);
    ushort_t* wbfy = (ushort_t*)((char*)d_ws + 34179072);
    float* off0  = (float*)((char*)d_ws + 34203648);
    float* off1  = (float*)((char*)d_ws + 37349376);
    float* poff  = (float*)((char*)d_ws + 40495104);
    ushort_t* zbuf = (ushort_t*)((char*)d_ws + 40495104);
    float* part  = (float*)((char*)d_ws + 107603968);
    float* stats = (float*)((char*)d_ws + 108652544);
    (void)ws_size;

    k_xbf<<<4353, 256, 0, stream>>>(x, xbf);
    k_wpack<<<240, 256, 0, stream>>>(w0, wx, wy, w0bf, wbfx, wbfy);
    k_offp<<<dim3(128,32), 256, 0, stream>>>(x, owx, owy, poff);
    // conv0 | offred (2048 + 4096 blocks)
    k_mid<<<6144, 256, 0, stream>>>(xbf, w0bf, g0, b0, m0, v0, poff,
        ogx, ovx, obx, omx, obbx,
        ogy, ovy, oby, omy, obby,
        off0, off1, out);
    k_dsc2m<<<dim3(4,256,8), 256, 0, stream>>>(xbf, off0, off1, wbfx, wbfy, bwx, bwy, zbuf, part);
    k_gnfinal2<<<128, 256, 0, stream>>>(part, stats);
    k_gnapply<<<32768, 256, 0, stream>>>(out, zbuf, stats, ggx, gbx, ggy, gby);
}

// Round 23
// 253.429 us; speedup vs baseline: 1.0867x; 1.0015x over previous
//
#include <hip/hip_runtime.h>
#include <hip/hip_bf16.h>
#include <math.h>

#define TS 256
#define HW 65536
#define CIN 64
#define EPSV 1e-5f
#define XPITCH 258   // padded row width (cols -1..256); rows padded too (i = -1..256)
// xbf layout (row-major): (((b*258 + row)*XPITCH) + col)*64 + c

typedef __attribute__((ext_vector_type(8))) short bf16x8;
typedef __attribute__((ext_vector_type(4))) float f32x4;
typedef __attribute__((ext_vector_type(16))) float f32x16;
typedef __attribute__((ext_vector_type(4))) unsigned short u16x4;
typedef unsigned short ushort_t;

__device__ __forceinline__ float silu_f(float v){ return v / (1.0f + expf(-v)); }
__device__ __forceinline__ ushort_t f2bf(float f){
    __hip_bfloat16 h = __float2bfloat16(f);
    return *reinterpret_cast<ushort_t*>(&h);
}
__device__ __forceinline__ float bf2f(ushort_t u){
    unsigned int t = ((unsigned int)u) << 16;
    return __uint_as_float(t);
}

// ---------------- x -> xbf bf16 (blocks 0..4352) | wpack (blocks 4353..4592) ----------------
__global__ __launch_bounds__(256) void k_xbf(const float* __restrict__ x, ushort_t* __restrict__ xbf,
        const float* __restrict__ w0, const float* __restrict__ wx, const float* __restrict__ wy,
        ushort_t* __restrict__ w0bf, ushort_t* __restrict__ wbfx, ushort_t* __restrict__ wbfy){
    int blk = blockIdx.x;
    int tid = threadIdx.x;
    if (blk < 4096){
        __shared__ float tile[64][65];
        int b = blk >> 10;
        int chunk = blk & 1023;
        int p0 = chunk * 64;
        int i = p0 >> 8, jb = p0 & 255;
        int lane = tid & 63, grp = tid >> 6;
        #pragma unroll
        for (int k = 0; k < 16; ++k){
            int c = k*4 + grp;
            tile[lane][c] = x[((size_t)(b*CIN + c))*HW + p0 + lane];
        }
        __syncthreads();
        #pragma unroll
        for (int k = 0; k < 16; ++k){
            int pp = k*4 + grp;
            xbf[(((size_t)b*258 + (i+1))*XPITCH + 1 + jb + pp)*64 + lane] = f2bf(tile[pp][lane]);
        }
    } else if (blk < 4353){
        int base = (blk - 4096) * 1024;
        #pragma unroll
        for (int k = 0; k < 4; ++k){
            int h = base + k*256 + tid;
            if (h < 132096){
                int b = h / 33024;
                int rem = h - b*33024;
                int r = (rem >= 16512) ? 257 : 0;
                int e = (rem >= 16512) ? rem - 16512 : rem;
                xbf[((size_t)b*258 + r)*XPITCH*64 + e] = 0;
            } else if (h < 263168){
                int h2 = h - 132096;
                int b = h2 >> 15;
                int rem = h2 & 32767;
                int row = rem >> 7;
                int rem2 = rem & 127;
                int colsel = rem2 >> 6;
                int c = rem2 & 63;
                xbf[(((size_t)b*258 + row + 1)*XPITCH + (colsel ? 257 : 0))*64 + c] = 0;
            }
        }
    } else {
        // wpack role (byte-for-byte r22 k_wpack body)
        int idx = (blk - 4353)*256 + tid;   // 0..61439
        if (idx < 36864){
            int r = idx >> 12;
            int rem = idx & 4095;
            int o = rem >> 6, c = rem & 63;
            w0bf[idx] = f2bf(w0[(o*64 + c)*9 + r]);
        } else {
            int k2 = idx - 36864;
            int set = k2 / 12288;
            int rem = k2 - set*12288;
            int o = rem / 192;
            int k = rem - o*192;
            int t = k >> 6, c = k & 63;
            const float* w = set ? wy : wx;
            ushort_t* dst = set ? wbfy : wbfx;
            dst[rem] = f2bf(w[(o*64 + c)*3 + t]);
        }
    }
}

// ---------------- offset conv partials: 8-ch chunk, 2 output rows, exact f32 (r14 verbatim) ----------------
__global__ __launch_bounds__(256) void k_offp(const float* __restrict__ x,
        const float* __restrict__ owx, const float* __restrict__ owy,
        float* __restrict__ poff){
    __shared__ float xs[8][4][258];
    __shared__ float wsm[4][8][9];
    int by = blockIdx.y;          // b*8 + chunk
    int b = by >> 3, chunk = by & 7;
    int i0 = blockIdx.x * 2;
    int tid = threadIdx.x;
    for (int idx = tid; idx < 4*8*9; idx += 256){
        int o = idx / 72;
        int rem = idx - o*72;
        int c = rem / 9, tap = rem - c*9;
        int morph = o >> 1;
        int ch = (o==0)?0:(o==1)?2:(o==2)?3:5;
        const float* w = morph ? owy : owx;
        wsm[o][c][tap] = w[(ch*64 + chunk*8 + c)*9 + tap];
    }
    for (int idx = tid; idx < 8*4*258; idx += 256){
        int c = idx / 1032;
        int rem = idx - c*1032;
        int rr = rem / 258, col = rem - rr*258;
        int gy = i0 + rr - 1, gx = col - 1;
        float v = 0.f;
        if (gy >= 0 && gy < 256 && gx >= 0 && gx < 256)
            v = x[((size_t)(b*64 + chunk*8 + c))*HW + gy*256 + gx];
        xs[c][rr][col] = v;
    }
    __syncthreads();
    float acc[4][2];
    #pragma unroll
    for (int o = 0; o < 4; ++o){ acc[o][0]=0.f; acc[o][1]=0.f; }
    int j = tid;
    #pragma unroll
    for (int c = 0; c < 8; ++c){
        float vrow[4][3];
        #pragma unroll
        for (int rr = 0; rr < 4; ++rr){
            vrow[rr][0] = xs[c][rr][j];
            vrow[rr][1] = xs[c][rr][j+1];
            vrow[rr][2] = xs[c][rr][j+2];
        }
        #pragma unroll
        for (int o = 0; o < 4; ++o){
            const float* wr = wsm[o][c];
            #pragma unroll
            for (int ky = 0; ky < 3; ++ky){
                #pragma unroll
                for (int kx = 0; kx < 3; ++kx){
                    float wv = wr[ky*3+kx];
                    acc[o][0] += wv * vrow[ky][kx];
                    acc[o][1] += wv * vrow[ky+1][kx];
                }
            }
        }
    }
    #pragma unroll
    for (int o = 0; o < 4; ++o){
        size_t base = ((size_t)((chunk*4 + o)*4 + b))*HW;
        poff[base + (size_t)i0*256 + j]     = acc[o][0];
        poff[base + (size_t)(i0+1)*256 + j] = acc[o][1];
    }
}

// ================= k_mid: {conv0 2-row x 64-px tile, 32x32 MFMA (0..2047)} | {offred (2048..6143)} =================
__global__ __launch_bounds__(256) void k_mid(
        const ushort_t* __restrict__ xbf, const ushort_t* __restrict__ w0bf,
        const float* __restrict__ g0, const float* __restrict__ b0,
        const float* __restrict__ m0, const float* __restrict__ v0,
        const float* __restrict__ poff,
        const float* __restrict__ ogx, const float* __restrict__ ovx,
        const float* __restrict__ obx, const float* __restrict__ omx,
        const float* __restrict__ obbx,
        const float* __restrict__ ogy, const float* __restrict__ ovy,
        const float* __restrict__ oby, const float* __restrict__ omy,
        const float* __restrict__ obby,
        float* __restrict__ off0, float* __restrict__ off1,
        float* __restrict__ out){
    // Xs: 4 rows x 66 px x 64 ch bf16, byte = rr*8448 + p*128 + ((c*2)^((p&7)<<4)); 33,792 B
    __shared__ __align__(16) ushort_t Xs[4*66*64];
    int blk = blockIdx.x;
    int tid = threadIdx.x;
    if (blk < 2048){
        // ---- conv0 role: block = (b, row-pair, 64-px quarter) ----
        int id2 = ((blk & 7) << 8) + (blk >> 3);   // XCD-banded
        int b  = id2 >> 9;
        int ip = (id2 >> 2) & 127;
        int jq = id2 & 3;
        int i0 = ip*2;
        int j0 = jq*64;
        int wv = tid >> 6;
        int lane = tid & 63;
        int l31 = lane & 31;
        int kh = lane >> 5;
        int row = wv >> 1;            // 0..1
        int obase = (wv & 1) * 32;

        for (int idx = tid; idx < 2112; idx += 256){
            int rr = idx / 528;
            int rem = idx - rr*528;
            int p = rem >> 3, cgrp = rem & 7;
            bf16x8 v = *(const bf16x8*)(xbf + (((size_t)b*258 + (i0 + rr))*XPITCH + j0 + p)*64 + cgrp*8);
            int byte = rr*8448 + p*128 + ((cgrp*16) ^ ((p & 7) << 4));
            *(bf16x8*)((char*)Xs + byte) = v;
        }
        __syncthreads();

        bf16x8 af[9][4];
        #pragma unroll
        for (int r = 0; r < 9; ++r)
            #pragma unroll
            for (int kg = 0; kg < 4; ++kg)
                af[r][kg] = *(const bf16x8*)(w0bf + (size_t)r*4096 + (obase + l31)*64 + kg*16 + kh*8);

        f32x16 acc0, acc1;
        #pragma unroll
        for (int e = 0; e < 16; ++e){ acc0[e] = 0.f; acc1[e] = 0.f; }

        #pragma unroll
        for (int r = 0; r < 9; ++r){
            const int rr = row + r/3;
            const int dx = r%3 - 1;
            #pragma unroll
            for (int kg = 0; kg < 4; ++kg){
                int cb = kg*32 + kh*16;
                int p0_ = l31 + dx + 1;
                bf16x8 b0_ = *(const bf16x8*)((char*)Xs + rr*8448 + p0_*128 + (cb ^ ((p0_ & 7) << 4)));
                acc0 = __builtin_amdgcn_mfma_f32_32x32x16_bf16(af[r][kg], b0_, acc0, 0, 0, 0);
                int p1_ = p0_ + 32;
                bf16x8 b1_ = *(const bf16x8*)((char*)Xs + rr*8448 + p1_*128 + (cb ^ ((p1_ & 7) << 4)));
                acc1 = __builtin_amdgcn_mfma_f32_32x32x16_bf16(af[r][kg], b1_, acc1, 0, 0, 0);
            }
        }
        int i = i0 + row;
        #pragma unroll
        for (int reg = 0; reg < 16; ++reg){
            int o = obase + (reg & 3) + 8*(reg >> 2) + 4*kh;
            float s = g0[o] * rsqrtf(v0[o] + EPSV);
            float bi = b0[o] - m0[o]*s;
            int j = j0 + l31;
            out[((size_t)(b*192 + o))*HW + i*TS + j]      = silu_f(acc0[reg]*s + bi);
            out[((size_t)(b*192 + o))*HW + i*TS + j + 32] = silu_f(acc1[reg]*s + bi);
        }
    } else {
        // ---- offred role: planes 0,2 only ----
        int idx = (blk - 2048)*256 + tid;
        int px = idx & 65535;
        int t2 = idx >> 16;
        int b = t2 & 3;
        int o6 = t2 >> 2;
        float s_ = 0.f;
        #pragma unroll
        for (int chunk = 0; chunk < 8; ++chunk)
            s_ += poff[((size_t)((chunk*4 + o6)*4 + b))*HW + px];
        int morph = o6 >> 1;
        int ch = (o6==0)?0:(o6==1)?2:(o6==2)?3:5;
        const float* og_ = morph? ogy:ogx; const float* ov_ = morph? ovy:ovx;
        const float* ob_ = morph? oby:obx; const float* om_ = morph? omy:omx;
        const float* obb_ = morph? obby:obbx;
        float sc = og_[ch]*rsqrtf(ov_[ch]+EPSV);
        float bi = (ob_[ch]-om_[ch])*sc + obb_[ch];
        int pl = (o6 & 1)*2;
        float* dst = (morph? off1:off0) + ((size_t)(b*3+pl))*HW;
        dst[px] = tanhf(s_*sc + bi);
    }
}

// ---------------- DSC both morphs: LDS-staged local window gather -> LDS bf16 -> MFMA ----------------
__global__ __launch_bounds__(256) void k_dsc2m(const ushort_t* __restrict__ xbf,
        const float* __restrict__ off0, const float* __restrict__ off1,
        const ushort_t* __restrict__ wbfx, const ushort_t* __restrict__ wbfy,
        const float* __restrict__ bwx, const float* __restrict__ bwy,
        ushort_t* __restrict__ zbuf, float* __restrict__ part){
    __shared__ __align__(16) ushort_t Vt[3*64*64];
    __shared__ __align__(16) ushort_t Xg[7][4][64];
    int mz = blockIdx.z;
    int b = mz & 3;
    int morph = mz >> 2;
    int i = blockIdx.y;
    int j0 = blockIdx.x * 64;
    int tid = threadIdx.x;
    int lane16 = tid & 15;
    int pq = tid >> 4;
    const float fi = (float)i;
    const float* offm = morph ? off1 : off0;

    if (morph == 0){
        int vec = tid >> 4;       // 0..15
        int s = vec >> 2, cs = vec & 3;
        int row = min(max(i - 1 + s, 0), 255);
        int col = min(max(i - 2 + cs, 0), 255);
        *(u16x4*)&Xg[s][cs][lane16*4] =
            *(const u16x4*)(xbf + ((size_t)(row+1)*XPITCH + 1 + col)*64 + lane16*4);
    } else {
        if (tid < 112){
            int s = tid >> 4;     // 0..6
            int row = min(max(i - 3 + s, 0), 255);
            *(u16x4*)&Xg[s][0][lane16*4] =
                *(const u16x4*)(xbf + ((size_t)(row+1)*XPITCH + 1 + i)*64 + lane16*4);
        }
    }
    __syncthreads();

    #pragma unroll
    for (int it = 0; it < 12; ++it){
        int pair = it*16 + pq;
        int t = pair >> 6, jloc = pair & 63;
        float y, wx1, wx0;
        int x0i, x1i;
        if (morph == 0){
            int j = j0 + jloc;
            float off = (t == 1) ? 0.f : offm[((size_t)(b*3 + t)*TS + i)*TS + j];
            y = fi + off;
            float vp = (t==0) ? -2.0f : ((t==1) ? -0.5f : 1.0f);
            float xf = fi + vp;
            float x0 = fminf(fmaxf(floorf(xf), 0.f), 255.f);
            float x1 = fminf(fmaxf(floorf(xf) + 1.f, 0.f), 255.f);
            wx1 = x1 - xf; wx0 = xf - x0;
            x0i = (int)x0; x1i = (int)x1;
        } else {
            int q = 3*(j0 + jloc) + t;
            int dl = q >> 8, jj = q & 255;
            float off = (dl == 1) ? 0.f : offm[((size_t)(b*3 + dl)*TS + i)*TS + jj];
            float vp = (dl==0) ? -2.0f : ((dl==1) ? -0.5f : 1.0f);
            y = fi + vp + off;
            wx1 = (i < 255) ? 1.f : 0.f; wx0 = 0.f;
            x0i = i; x1i = i;
        }
        float yf = floorf(y);
        float y0 = fminf(fmaxf(yf, 0.f), 255.f);
        float y1 = fminf(fmaxf(yf + 1.f, 0.f), 255.f);
        float wy1 = y1 - y, wy0 = y - y0;
        int y0i = (int)y0, y1i = (int)y1;
        int c0 = lane16*4;
        int rbase = morph ? (i - 3) : (i - 1);
        int rs0 = y0i - rbase;
        int rs1 = y1i - rbase;
        int cs0 = morph ? 0 : (x0i - (i - 2));
        u16x4 a  = *(const u16x4*)&Xg[rs0][cs0][c0];
        u16x4 c_ = *(const u16x4*)&Xg[rs1][cs0][c0];
        float v[4];
        if (morph == 0 && wx0 != 0.f){
            int cs1 = x1i - (i - 2);
            u16x4 bv = *(const u16x4*)&Xg[rs0][cs1][c0];
            u16x4 d  = *(const u16x4*)&Xg[rs1][cs1][c0];
            #pragma unroll
            for (int k = 0; k < 4; ++k)
                v[k] = wy1*(wx1*bf2f(a[k]) + wx0*bf2f(bv[k]))
                     + wy0*(wx1*bf2f(c_[k]) + wx0*bf2f(d[k]));
        } else {
            #pragma unroll
            for (int k = 0; k < 4; ++k)
                v[k] = wx1*(wy1*bf2f(a[k]) + wy0*bf2f(c_[k]));
        }
        unsigned int lo = (unsigned int)f2bf(v[0]) | ((unsigned int)f2bf(v[1]) << 16);
        unsigned int hi = (unsigned int)f2bf(v[2]) | ((unsigned int)f2bf(v[3]) << 16);
        int cbyte = (c0*2) ^ ((jloc & 7) << 4);
        uint2 pk; pk.x = lo; pk.y = hi;
        *(uint2*)((char*)Vt + t*8192 + jloc*128 + cbyte) = pk;
    }
    __syncthreads();

    const ushort_t* wbf = morph ? wbfy : wbfx;
    const float* wb = morph ? bwy : bwx;
    ushort_t* zb = zbuf + (size_t)morph*4*64*HW;

    int wv = tid >> 6;
    int lane = tid & 63;
    int l15 = lane & 15, lhi = lane >> 4;
    int mi = wv;
    f32x4 acc[4];
    #pragma unroll
    for (int ni = 0; ni < 4; ++ni) acc[ni] = (f32x4){0.f,0.f,0.f,0.f};
    bf16x8 af[6];
    #pragma unroll
    for (int ks = 0; ks < 6; ++ks)
        af[ks] = *(const bf16x8*)(wbf + (mi*16 + l15)*192 + ks*32 + lhi*8);
    #pragma unroll
    for (int ks = 0; ks < 6; ++ks){
        int t = ks >> 1;
        int cbyte = ((ks & 1)*32 + lhi*8)*2;
        #pragma unroll
        for (int ni = 0; ni < 4; ++ni){
            int j = ni*16 + l15;
            bf16x8 bfr = *(const bf16x8*)((char*)Vt + t*8192 + j*128 + (cbyte ^ ((j & 7) << 4)));
            acc[ni] = __builtin_amdgcn_mfma_f32_16x16x32_bf16(af[ks], bfr, acc[ni], 0, 0, 0);
        }
    }
    float rsum[4], rsq[4];
    #pragma unroll
    for (int reg = 0; reg < 4; ++reg){
        int o = mi*16 + lhi*4 + reg;
        float bias = wb[o];
        float rs = 0.f, rq = 0.f;
        #pragma unroll
        for (int ni = 0; ni < 4; ++ni){
            int j = j0 + ni*16 + l15;
            float val = acc[ni][reg] + bias;
            zb[((size_t)b*64 + o)*HW + i*TS + j] = f2bf(val);
            rs += val; rq += val*val;
        }
        #pragma unroll
        for (int m = 1; m < 16; m <<= 1){
            rs += __shfl_xor(rs, m, 64);
            rq += __shfl_xor(rq, m, 64);
        }
        rsum[reg] = rs; rsq[reg] = rq;
    }
    if (l15 == 0){
        float ts = rsum[0]+rsum[1]+rsum[2]+rsum[3];
        float tq = rsq[0]+rsq[1]+rsq[2]+rsq[3];
        int g = mi*4 + lhi;
        size_t slot = (((size_t)(morph*4 + b)*16 + g)*1024) + (blockIdx.y*4 + blockIdx.x);
        part[slot*2]   = ts;
        part[slot*2+1] = tq;
    }
}

// ---------------- GN final: reduce 1024 partials per (m,b,g) ----------------
__global__ __launch_bounds__(256) void k_gnfinal2(const float* __restrict__ part, float* __restrict__ stats){
    int slot = blockIdx.x;
    float s = 0.f, q = 0.f;
    for (int k = threadIdx.x; k < 1024; k += 256){
        s += part[((size_t)slot*1024 + k)*2];
        q += part[((size_t)slot*1024 + k)*2 + 1];
    }
    #pragma unroll
    for (int d = 32; d > 0; d >>= 1){ s += __shfl_down(s, d, 64); q += __shfl_down(q, d, 64); }
    __shared__ float rs[4], rq[4];
    int lane = threadIdx.x & 63, wv = threadIdx.x >> 6;
    if (lane == 0){ rs[wv] = s; rq[wv] = q; }
    __syncthreads();
    if (threadIdx.x == 0){
        float S = rs[0]+rs[1]+rs[2]+rs[3];
        float Q = rq[0]+rq[1]+rq[2]+rq[3];
        float inv = 1.f/262144.f;
        float mean = S*inv;
        float var = Q*inv - mean*mean;
        stats[slot*2] = mean;
        stats[slot*2+1] = rsqrtf(var + EPSV);
    }
}

// ---------------- GN apply: read bf16 z, write f32 out (both morphs) ----------------
__global__ __launch_bounds__(256) void k_gnapply(float* __restrict__ dout, const ushort_t* __restrict__ zb,
        const float* __restrict__ stats,
        const float* __restrict__ ggx, const float* __restrict__ gbx,
        const float* __restrict__ ggy, const float* __restrict__ gby){
    int idx = blockIdx.x*256 + threadIdx.x;
    int pix4 = idx & 16383;
    int chb = idx >> 14;
    int ch = chb & 127;
    int b = chb >> 7;
    int m = ch >> 6;
    int cc = ch & 63;
    int g = cc >> 2;
    const float* gg = m ? ggy : ggx;
    const float* gb = m ? gby : gbx;
    int si = ((m*4 + b)*16 + g)*2;
    float mean = stats[si], rsig = stats[si+1];
    float sc = rsig * gg[cc];
    float bi = gb[cc] - mean*sc;
    u16x4 zv = *(const u16x4*)(zb + (((size_t)(m*4 + b)*64 + cc)*HW) + (size_t)pix4*4);
    float4 v;
    v.x = silu_f(bf2f(zv[0])*sc + bi);
    v.y = silu_f(bf2f(zv[1])*sc + bi);
    v.z = silu_f(bf2f(zv[2])*sc + bi);
    v.w = silu_f(bf2f(zv[3])*sc + bi);
    float4* ptr = (float4*)(dout + ((size_t)(b*192 + 64 + ch))*HW) + pix4;
    *ptr = v;
}

extern "C" void kernel_launch(void* const* d_in, const int* in_sizes, int n_in,
                              void* d_out, int out_size, void* d_ws, size_t ws_size,
                              hipStream_t stream){
    const float* x    = (const float*)d_in[0];
    const float* w0   = (const float*)d_in[1];
    const float* g0   = (const float*)d_in[2];
    const float* b0   = (const float*)d_in[3];
    const float* m0   = (const float*)d_in[4];
    const float* v0   = (const float*)d_in[5];
    const float* owx  = (const float*)d_in[6];
    const float* obx  = (const float*)d_in[7];
    const float* ogx  = (const float*)d_in[8];
    const float* obbx = (const float*)d_in[9];
    const float* omx  = (const float*)d_in[10];
    const float* ovx  = (const float*)d_in[11];
    const float* wx   = (const float*)d_in[12];
    const float* bwx  = (const float*)d_in[13];
    const float* ggx  = (const float*)d_in[14];
    const float* gbx  = (const float*)d_in[15];
    const float* owy  = (const float*)d_in[16];
    const float* oby  = (const float*)d_in[17];
    const float* ogy  = (const float*)d_in[18];
    const float* obby = (const float*)d_in[19];
    const float* omy  = (const float*)d_in[20];
    const float* ovy  = (const float*)d_in[21];
    const float* wy   = (const float*)d_in[22];
    const float* bwy  = (const float*)d_in[23];
    const float* ggy  = (const float*)d_in[24];
    const float* gby  = (const float*)d_in[25];

    float* out = (float*)d_out;
    // ws layout (bytes):
    //   xbf   @ 0          : 34,080,768
    //   w0bf  @ 34,080,768 : 73,728
    //   wbfx  @ 34,154,496 : 24,576
    //   wbfy  @ 34,179,072 : 24,576
    //   off0  @ 34,203,648 : 3,145,728
    //   off1  @ 37,349,376 : 3,145,728
    //   poff  @ 40,495,104 : 33,554,432   (dead after k_mid)
    //   zbuf  @ 40,495,104 : 67,108,864   (aliases poff)
    //   part  @ 107,603,968: 1,048,576
    //   stats @ 108,652,544: 1,024
    ushort_t* xbf  = (ushort_t*)d_ws;
    ushort_t* w0bf = (ushort_t*)((char*)d_ws + 34080768);
    ushort_t* wbfx = (ushort_t*)((char*)d_ws + 34154496);
    ushort_t* wbfy = (ushort_t*)((char*)d_ws + 34179072);
    float* off0  = (float*)((char*)d_ws + 34203648);
    float* off1  = (float*)((char*)d_ws + 37349376);
    float* poff  = (float*)((char*)d_ws + 40495104);
    ushort_t* zbuf = (ushort_t*)((char*)d_ws + 40495104);
    float* part  = (float*)((char*)d_ws + 107603968);
    float* stats = (float*)((char*)d_ws + 108652544);
    (void)ws_size;

    // xbf + halos + wpack (4096 + 257 + 240 = 4593 blocks)
    k_xbf<<<4593, 256, 0, stream>>>(x, xbf, w0, wx, wy, w0bf, wbfx, wbfy);
    k_offp<<<dim3(128,32), 256, 0, stream>>>(x, owx, owy, poff);
    // conv0 | offred (2048 + 4096 blocks)
    k_mid<<<6144, 256, 0, stream>>>(xbf, w0bf, g0, b0, m0, v0, poff,
        ogx, ovx, obx, omx, obbx,
        ogy, ovy, oby, omy, obby,
        off0, off1, out);
    k_dsc2m<<<dim3(4,256,8), 256, 0, stream>>>(xbf, off0, off1, wbfx, wbfy, bwx, bwy, zbuf, part);
    k_gnfinal2<<<128, 256, 0, stream>>>(part, stats);
    k_gnapply<<<32768, 256, 0, stream>>>(out, zbuf, stats, ggx, gbx, ggy, gby);
}